// Round 10
// baseline (6415.520 us; speedup 1.0000x reference)
//
#include <hip/hip_runtime.h>
#include <math.h>

#define NN 4096
#define DD 512
#define NSL 16
#define SCALE_F 0.044194173824159216f
#define LN_EPS_F 1e-5f
#define ATTN_EPS_F 1e-8f

typedef float4 f4;
typedef __fp16 h2 __attribute__((ext_vector_type(2)));
typedef _Float16 h2f __attribute__((ext_vector_type(2)));

__device__ __forceinline__ float dot4f(f4 a, f4 b){
    return a.x*b.x + a.y*b.y + a.z*b.z + a.w*b.w;
}
__device__ __forceinline__ float fdot2u(unsigned a, unsigned b, float c){
    return __builtin_amdgcn_fdot2(__builtin_bit_cast(h2f, a),
                                  __builtin_bit_cast(h2f, b), c, false);
}
__device__ __forceinline__ unsigned pk(float x, float y){
    return __builtin_bit_cast(unsigned, __builtin_amdgcn_cvt_pkrtz(x, y));
}

// ---- pre: slots bcast + per-row f32 stats of v,k + f16 copy of k ----
// grid 1024 x 256. Coalesced: 16 lanes per row.
__global__ __launch_bounds__(256) void k_pre(const float* __restrict__ mu,
        const float* __restrict__ kin, const float* __restrict__ vin,
        float* __restrict__ slots, float* __restrict__ kmu, float* __restrict__ krstd,
        float* __restrict__ vmu, float* __restrict__ vrstd,
        __fp16* __restrict__ kh){
    int bx = blockIdx.x, t = threadIdx.x;
    if (bx < 128){
        int idx = bx*256 + t;                      // 32768 f4
        ((f4*)slots)[idx] = ((const f4*)mu)[idx & 2047];
    }
    int sub = t & 15;            // lane within row
    int rl  = t >> 4;            // 16 rows per pass
#pragma unroll
    for (int pass = 0; pass < 8; pass++){
        int task = bx*128 + pass*16 + rl;          // 0..131071
        int half = task >> 16;                     // 0: v, 1: k
        int row  = task & 65535;
        const float* src = half ? kin : vin;
        const f4* r4 = (const f4*)(src + (size_t)row*DD);
        uint2* w2 = (uint2*)(kh + (size_t)row*DD);
        float s = 0.f, ss = 0.f;
#pragma unroll
        for (int k2 = 0; k2 < 8; k2++){
            f4 x = r4[sub + k2*16];
            s  += x.x+x.y+x.z+x.w;
            ss += x.x*x.x+x.y*x.y+x.z*x.z+x.w*x.w;
            if (half){
                uint2 o; o.x = pk(x.x, x.y); o.y = pk(x.z, x.w);
                w2[sub + k2*16] = o;
            }
        }
        for (int o = 1; o < 16; o <<= 1){
            s += __shfl_xor(s, o); ss += __shfl_xor(ss, o);
        }
        if (sub == 0){
            float m = s*(1.f/DD);
            float rs = rsqrtf(ss*(1.f/DD) - m*m + LN_EPS_F);
            if (half){ kmu[row] = m; krstd[row] = rs; }
            else     { vmu[row] = m; vrstd[row] = rs; }
        }
    }
}

// ---- transpose-pack weights: TW[kk][c] = f4(W[c][4kk..4kk+3]) ----
__global__ __launch_bounds__(256) void k_wt(const float* __restrict__ Wq,
        const float* __restrict__ Wih, const float* __restrict__ Whh,
        const float* __restrict__ W1, const float* __restrict__ W2,
        f4* __restrict__ TWq, f4* __restrict__ TWih, f4* __restrict__ TWhh,
        f4* __restrict__ TW1, f4* __restrict__ TW2){
    int id = blockIdx.x*256 + threadIdx.x;
    const float* W; f4* TW; int R, local;
    if (id < 65536)      { W = Wq;  TW = TWq;  R = 512;  local = id; }
    else if (id < 262144){ W = Wih; TW = TWih; R = 1536; local = id - 65536; }
    else if (id < 458752){ W = Whh; TW = TWhh; R = 1536; local = id - 262144; }
    else if (id < 524288){ W = W1;  TW = TW1;  R = 512;  local = id - 458752; }
    else                 { W = W2;  TW = TW2;  R = 512;  local = id - 524288; }
    int kk = local / R, c = local - kk*R;
    TW[local] = ((const f4*)W)[(size_t)c*128 + kk];
}

// ---- fused LN(slots) + q-projection (coalesced TWq) ----
__global__ __launch_bounds__(256) void k_ln_q(const float* __restrict__ slots,
        const float* __restrict__ gs, const float* __restrict__ bs,
        const f4* __restrict__ TWq, const float* __restrict__ bq,
        const float* __restrict__ gk, const float* __restrict__ bk,
        float* __restrict__ qg, float* __restrict__ C1p, float* __restrict__ C2p){
    __shared__ __align__(16) float rowL[4*DD];
    int lane = threadIdx.x & 63, wv = threadIdx.x >> 6;
    int m = blockIdx.y*4 + wv;
    int c = blockIdx.x*64 + lane;
    const f4* r4 = (const f4*)(slots + (size_t)m*DD);
    f4 v0 = r4[lane*2], v1 = r4[lane*2+1];
    float s  = v0.x+v0.y+v0.z+v0.w + v1.x+v1.y+v1.z+v1.w;
    float ss = v0.x*v0.x+v0.y*v0.y+v0.z*v0.z+v0.w*v0.w
             + v1.x*v1.x+v1.y*v1.y+v1.z*v1.z+v1.w*v1.w;
    for (int o = 32; o; o >>= 1){ s += __shfl_down(s,o); ss += __shfl_down(ss,o); }
    s = __shfl(s,0); ss = __shfl(ss,0);
    float mu = s*(1.f/DD);
    float rstd = rsqrtf(ss*(1.f/DD) - mu*mu + LN_EPS_F);
    const f4* g4 = (const f4*)gs; const f4* b4 = (const f4*)bs;
    f4 g0 = g4[lane*2], g1 = g4[lane*2+1], c0 = b4[lane*2], c1 = b4[lane*2+1];
    f4 o0, o1;
    o0.x=(v0.x-mu)*rstd*g0.x+c0.x; o0.y=(v0.y-mu)*rstd*g0.y+c0.y;
    o0.z=(v0.z-mu)*rstd*g0.z+c0.z; o0.w=(v0.w-mu)*rstd*g0.w+c0.w;
    o1.x=(v1.x-mu)*rstd*g1.x+c1.x; o1.y=(v1.y-mu)*rstd*g1.y+c1.y;
    o1.z=(v1.z-mu)*rstd*g1.z+c1.z; o1.w=(v1.w-mu)*rstd*g1.w+c1.w;
    f4* rw = (f4*)(rowL + wv*DD);
    rw[lane*2] = o0; rw[lane*2+1] = o1;
    __syncthreads();
    float acc = 0.f;
    for (int kk = 0; kk < 128; kk++)
        acc += dot4f(rw[kk], TWq[(size_t)kk*512 + c]);
    float q0 = acc + bq[c];
    float qg0 = q0 * gk[c];
    qg[(size_t)m*DD + c] = qg0;
    float r1 = qg0, r2 = q0 * bk[c];
    for (int o = 32; o; o >>= 1){ r1 += __shfl_down(r1,o); r2 += __shfl_down(r2,o); }
    if (lane == 0){
        C1p[blockIdx.x*256 + m] = r1;
        C2p[blockIdx.x*256 + m] = r2;
    }
}

// ---- fused QK^T + inverted softmax + AV partial (f16 k, f32 v) ----
// grid (64 chunks of 64 j, 16 b) = 1024 blocks. rep = diagnostic repeat.
__global__ __launch_bounds__(256, 4) void k_attn_av(const __fp16* __restrict__ kh,
        const float* __restrict__ vin, const float* __restrict__ qg,
        const float* __restrict__ C1p, const float* __restrict__ C2p,
        const float* __restrict__ kmu, const float* __restrict__ krstd,
        const float* __restrict__ vmu, const float* __restrict__ vrstd,
        float* __restrict__ Sp, float* __restrict__ Mp, float* __restrict__ Uwp,
        float* __restrict__ attn_out, int last, int rep){
    __shared__ __align__(16) uint4 qhL[1024];      // 16 KB packed f16 q
    __shared__ __align__(16) float wL[64*20];      // 5 KB
    __shared__ float c1s[NSL], c2s[NSL];
    __shared__ float spL[4][NSL], mpL[4][NSL];
    int chunk = blockIdx.x, b = blockIdx.y;
    int t = threadIdx.x, lane = t & 63, wv = t >> 6;
    int r = lane & 15, qq = lane >> 4;

    const f4* qgg = (const f4*)(qg + (size_t)b*NSL*DD);
    for (int e = t; e < 1024; e += 256){
        int dd = e >> 3, p = e & 7;
        f4 qa = qgg[(size_t)(2*p)*128 + dd];
        f4 qb = qgg[(size_t)(2*p+1)*128 + dd];
        uint4 u;
        u.x = pk(qa.x, qa.y);
        u.y = pk(qb.x, qb.y);
        u.z = pk(qa.z, qa.w);
        u.w = pk(qb.z, qb.w);
        qhL[e] = u;
    }
    if (t < NSL){
        float c1 = 0.f, c2 = 0.f;
#pragma unroll
        for (int k = 0; k < 8; k++){
            c1 += C1p[k*256 + b*NSL + t];
            c2 += C2p[k*256 + b*NSL + t];
        }
        c1s[t] = c1; c2s[t] = c2;
    }
    __syncthreads();

    for (int rr = 0; rr < rep; rr++){
        // ---- QK: thread owns quarter qq of row j (f16 k) ----
        int j = chunk*64 + wv*16 + r;
        const uint4* kr = (const uint4*)(kh + ((size_t)b*NN + j)*DD) + qq*16;
        float a[NSL];
#pragma unroll
        for (int i = 0; i < NSL; i++) a[i] = 0.f;
        uint4 kb = kr[0];
        for (int e = 0; e < 16; e++){
            uint4 nk;
            if (e < 15) nk = kr[e+1];
            int dd0 = qq*32 + e*2;
#pragma unroll
            for (int p = 0; p < 8; p++){
                uint4 u = qhL[dd0*8 + p];
                a[2*p]   = fdot2u(kb.x, u.x, a[2*p]);
                a[2*p+1] = fdot2u(kb.x, u.y, a[2*p+1]);
                a[2*p]   = fdot2u(kb.y, u.z, a[2*p]);
                a[2*p+1] = fdot2u(kb.y, u.w, a[2*p+1]);
                uint4 u2 = qhL[(dd0+1)*8 + p];
                a[2*p]   = fdot2u(kb.z, u2.x, a[2*p]);
                a[2*p+1] = fdot2u(kb.z, u2.y, a[2*p+1]);
                a[2*p]   = fdot2u(kb.w, u2.z, a[2*p]);
                a[2*p+1] = fdot2u(kb.w, u2.w, a[2*p+1]);
            }
            kb = nk;
        }
#pragma unroll
        for (int i = 0; i < NSL; i++){
            a[i] += __shfl_xor(a[i], 16);
            a[i] += __shfl_xor(a[i], 32);
        }
        float mu = kmu[(size_t)b*NN + j];
        float rstd = krstd[(size_t)b*NN + j];
        float mx = -1e30f;
#pragma unroll
        for (int i = 0; i < NSL; i++){
            a[i] = SCALE_F*(rstd*(a[i] - mu*c1s[i]) + c2s[i]);
            mx = fmaxf(mx, a[i]);
        }
        float se = 0.f;
#pragma unroll
        for (int i = 0; i < NSL; i++){ a[i] = __expf(a[i]-mx); se += a[i]; }
        float inv = 1.f/se;
        float rv = vrstd[(size_t)b*NN + j];
        float vm = vmu[(size_t)b*NN + j];
#pragma unroll
        for (int i = 0; i < NSL; i++) a[i] = a[i]*inv + ATTN_EPS_F;
#pragma unroll
        for (int i = 0; i < NSL; i++){
            float r1 = a[i], r2 = a[i]*rv*vm;
            for (int o = 1; o < 16; o <<= 1){ r1 += __shfl_xor(r1,o); r2 += __shfl_xor(r2,o); }
            if (lane == 0){ spL[wv][i] = r1; mpL[wv][i] = r2; }
        }
        if (qq == 0){
            int jl = wv*16 + r;
#pragma unroll
            for (int i = 0; i < NSL; i++) wL[jl*20 + i] = a[i]*rv;
            if (last){
#pragma unroll
                for (int i = 0; i < NSL; i++)
                    attn_out[((size_t)b*NSL + i)*NN + j] = a[i];
            }
        }
        __syncthreads();

        if (t < NSL)
            Sp[((size_t)b*NSL + t)*64 + chunk] = spL[0][t]+spL[1][t]+spL[2][t]+spL[3][t];
        else if (t < 2*NSL){
            int i = t - NSL;
            Mp[((size_t)b*NSL + i)*64 + chunk] = mpL[0][i]+mpL[1][i]+mpL[2][i]+mpL[3][i];
        }

        // ---- AV partial over this chunk's 64 j (f32 v) ----
        f4 ax[4], ay[4];
#pragma unroll
        for (int g2 = 0; g2 < 4; g2++){ ax[g2] = f4{0,0,0,0}; ay[g2] = f4{0,0,0,0}; }
        const float2* v2 = (const float2*)(vin + ((size_t)b*NN + (size_t)chunk*64)*DD);
#pragma unroll 2
        for (int jj = 0; jj < 64; jj++){
            float2 vv = v2[(size_t)jj*256 + t];
            const f4* wl4 = (const f4*)(wL + jj*20);
#pragma unroll
            for (int g2 = 0; g2 < 4; g2++){
                f4 wq = wl4[g2];
                ax[g2].x += wq.x*vv.x; ax[g2].y += wq.y*vv.x; ax[g2].z += wq.z*vv.x; ax[g2].w += wq.w*vv.x;
                ay[g2].x += wq.x*vv.y; ay[g2].y += wq.y*vv.y; ay[g2].z += wq.z*vv.y; ay[g2].w += wq.w*vv.y;
            }
        }
#pragma unroll
        for (int g2 = 0; g2 < 4; g2++){
            const float* px = (const float*)&ax[g2];
            const float* py = (const float*)&ay[g2];
#pragma unroll
            for (int c4 = 0; c4 < 4; c4++){
                int i = g2*4 + c4;
                float2 o2; o2.x = px[c4]; o2.y = py[c4];
                *(float2*)(Uwp + (((size_t)(b*NSL + i))*64 + chunk)*DD + 2*t) = o2;
            }
        }
        __syncthreads();
    }
}

// ---- updates = gv*(sum Uwp - M)/S + bv  (block = row m) ----
__global__ __launch_bounds__(256) void k_upd(const float* __restrict__ Uwp,
        const float* __restrict__ Sp, const float* __restrict__ Mp,
        const float* __restrict__ gv, const float* __restrict__ bv,
        float* __restrict__ upd){
    __shared__ float sm[2];
    int m = blockIdx.x, t = threadIdx.x;
    if (t < 128){
        float val = (t < 64) ? Sp[(size_t)m*64 + (t&63)] : Mp[(size_t)m*64 + (t&63)];
        for (int o = 1; o < 64; o <<= 1) val += __shfl_xor(val, o);
        if (t == 0)  sm[0] = val;
        if (t == 64) sm[1] = val;
    }
    __syncthreads();
    float Sv = sm[0], Mv = sm[1];
    float rS = 1.f/Sv;
    float2 acc; acc.x = 0.f; acc.y = 0.f;
    const float* base = Uwp + (size_t)m*64*DD + 2*t;
#pragma unroll 8
    for (int ch = 0; ch < 64; ch++){
        float2 u = *(const float2*)(base + (size_t)ch*DD);
        acc.x += u.x; acc.y += u.y;
    }
    float2 gvv = ((const float2*)gv)[t];
    float2 bvv = ((const float2*)bv)[t];
    float2 o2;
    o2.x = gvv.x*(acc.x - Mv)*rS + bvv.x;
    o2.y = gvv.y*(acc.y - Mv)*rS + bvv.y;
    *(float2*)(upd + (size_t)m*DD + 2*t) = o2;
}

// ---- GRU gate matmuls (coalesced TWih/TWhh). rep = diagnostic repeat ----
__global__ __launch_bounds__(256) void k_gru_mm(const float* __restrict__ x, const float* __restrict__ h,
        const f4* __restrict__ TWih, const float* __restrict__ bih,
        const f4* __restrict__ TWhh, const float* __restrict__ bhh,
        float* __restrict__ gp, int rep){
    int lane = threadIdx.x & 63, wv = threadIdx.x >> 6;
    int c = blockIdx.x*64 + lane;                 // 0..2047
    int m0 = blockIdx.y*16 + wv*4;
    int type = c >> 9;
    const f4* x4 = (const f4*)x;
    const f4* h4 = (const f4*)h;
    for (int rr = 0; rr < rep; rr++){
        float acc[4] = {0,0,0,0};
        float bias;
        if (type <= 1){
            for (int kk = 0; kk < 128; kk++){
                f4 aa = TWih[(size_t)kk*1536 + c];
                f4 bb = TWhh[(size_t)kk*1536 + c];
#pragma unroll
                for (int mm = 0; mm < 4; mm++)
                    acc[mm] += dot4f(aa, x4[(size_t)(m0+mm)*128+kk]) + dot4f(bb, h4[(size_t)(m0+mm)*128+kk]);
            }
            bias = bih[c] + bhh[c];
        } else if (type == 2){
            for (int kk = 0; kk < 128; kk++){
                f4 aa = TWih[(size_t)kk*1536 + c];
#pragma unroll
                for (int mm = 0; mm < 4; mm++)
                    acc[mm] += dot4f(aa, x4[(size_t)(m0+mm)*128+kk]);
            }
            bias = bih[c];
        } else {
            int cr = c - 512;
            for (int kk = 0; kk < 128; kk++){
                f4 aa = TWhh[(size_t)kk*1536 + cr];
#pragma unroll
                for (int mm = 0; mm < 4; mm++)
                    acc[mm] += dot4f(aa, h4[(size_t)(m0+mm)*128+kk]);
            }
            bias = bhh[cr];
        }
#pragma unroll
        for (int mm = 0; mm < 4; mm++)
            gp[(size_t)(m0+mm)*2048 + c] = acc[mm] + bias;
    }
}

// ---- GRU elementwise + LN(gff,bff) fused ----
__global__ __launch_bounds__(256) void k_gru_ln(const float* __restrict__ gp,
        const float* __restrict__ h, const float* __restrict__ gff, const float* __restrict__ bff,
        float* __restrict__ slots2, float* __restrict__ sbuf){
    __shared__ float sm[8];
    int m = blockIdx.x, t = threadIdx.x, lane = t & 63, wv = t >> 6;
    const float* g = gp + (size_t)m*2048;
    float2 rp = *(const float2*)(g + 2*t);
    float2 zp = *(const float2*)(g + 512 + 2*t);
    float2 nx = *(const float2*)(g + 1024 + 2*t);
    float2 nh = *(const float2*)(g + 1536 + 2*t);
    float2 hh = *(const float2*)(h + (size_t)m*DD + 2*t);
    float2 s2;
    {
        float r = 1.f/(1.f + __expf(-rp.x));
        float z = 1.f/(1.f + __expf(-zp.x));
        float n = tanhf(nx.x + r*nh.x);
        s2.x = (1.f - z)*n + z*hh.x;
        r = 1.f/(1.f + __expf(-rp.y));
        z = 1.f/(1.f + __expf(-zp.y));
        n = tanhf(nx.y + r*nh.y);
        s2.y = (1.f - z)*n + z*hh.y;
    }
    *(float2*)(slots2 + (size_t)m*DD + 2*t) = s2;
    float s = s2.x + s2.y;
    float ss = s2.x*s2.x + s2.y*s2.y;
    for (int o = 32; o; o >>= 1){ s += __shfl_down(s,o); ss += __shfl_down(ss,o); }
    if (lane == 0){ sm[wv] = s; sm[4+wv] = ss; }
    __syncthreads();
    float S = sm[0]+sm[1]+sm[2]+sm[3];
    float SS = sm[4]+sm[5]+sm[6]+sm[7];
    float mu = S*(1.f/DD);
    float rstd = rsqrtf(SS*(1.f/DD) - mu*mu + LN_EPS_F);
    float2 gg = *(const float2*)(gff + 2*t);
    float2 bb = *(const float2*)(bff + 2*t);
    float2 o2;
    o2.x = (s2.x-mu)*rstd*gg.x + bb.x;
    o2.y = (s2.y-mu)*rstd*gg.y + bb.y;
    *(float2*)(sbuf + (size_t)m*DD + 2*t) = o2;
}

// ---- FFN1 (coalesced TW1) ----
__global__ __launch_bounds__(256) void k_ffn1(const float* __restrict__ a, const f4* __restrict__ TW1,
                                              const float* __restrict__ b1, float* __restrict__ hid){
    int lane = threadIdx.x & 63, wv = threadIdx.x >> 6;
    int c = blockIdx.x*64 + lane;
    int m0 = blockIdx.y*16 + wv*4;
    const f4* a4 = (const f4*)a;
    float acc[4] = {0,0,0,0};
    for (int kk = 0; kk < 128; kk++){
        f4 w = TW1[(size_t)kk*512 + c];
#pragma unroll
        for (int mm = 0; mm < 4; mm++)
            acc[mm] += dot4f(w, a4[(size_t)(m0+mm)*128+kk]);
    }
    float bc = b1[c];
#pragma unroll
    for (int mm = 0; mm < 4; mm++)
        hid[(size_t)(m0+mm)*DD + c] = fmaxf(acc[mm] + bc, 0.f);
}

// ---- FFN2 (coalesced TW2) ----
__global__ __launch_bounds__(256) void k_ffn2(const float* __restrict__ hid, const f4* __restrict__ TW2,
                                              const float* __restrict__ b2, const float* __restrict__ slots2,
                                              float* __restrict__ slots, float* __restrict__ out_slots, int last){
    int lane = threadIdx.x & 63, wv = threadIdx.x >> 6;
    int d = blockIdx.x*64 + lane;
    int m0 = blockIdx.y*16 + wv*4;
    const f4* h4 = (const f4*)hid;
    float acc[4] = {0,0,0,0};
    for (int kk = 0; kk < 128; kk++){
        f4 w = TW2[(size_t)kk*512 + d];
#pragma unroll
        for (int mm = 0; mm < 4; mm++)
            acc[mm] += dot4f(w, h4[(size_t)(m0+mm)*128+kk]);
    }
    float bc = b2[d];
#pragma unroll
    for (int mm = 0; mm < 4; mm++){
        float v0 = slots2[(size_t)(m0+mm)*DD + d] + acc[mm] + bc;
        slots[(size_t)(m0+mm)*DD + d] = v0;
        if (last) out_slots[(size_t)(m0+mm)*DD + d] = v0;
    }
}

// ---- features ----
__global__ __launch_bounds__(256) void k_features(const float* __restrict__ prompts, const float* __restrict__ slots,
        const float* __restrict__ attn, float* __restrict__ pf, float* __restrict__ sf, float* __restrict__ sf2){
    int b = blockIdx.y;
    int pbase = blockIdx.x*32;
    int t = threadIdx.x;
    __shared__ float al[NSL][33];
    for (int idx = t; idx < NSL*32; idx += 256){
        int i = idx >> 5, pp = idx & 31;
        al[i][pp] = attn[((size_t)b*NSL + i)*NN + pbase + pp];
    }
    float2 pr[NSL], sl[NSL];
    const float2* p2 = (const float2*)prompts;
    const float2* s2 = (const float2*)(slots + (size_t)b*NSL*DD);
#pragma unroll
    for (int i = 0; i < NSL; i++){ pr[i] = p2[i*256+t]; sl[i] = s2[i*256+t]; }
    __syncthreads();
    for (int pp = 0; pp < 32; pp++){
        float a0=0.f, a1=0.f, c0=0.f, c1=0.f;
#pragma unroll
        for (int i = 0; i < NSL; i++){
            float a = al[i][pp];
            a0 += a*pr[i].x; a1 += a*pr[i].y;
            c0 += a*sl[i].x; c1 += a*sl[i].y;
        }
        size_t o = ((size_t)b*NN + pbase + pp)*DD + 2*t;
        float2 pv; pv.x=a0; pv.y=a1;
        float2 sv; sv.x=c0; sv.y=c1;
        *(float2*)(pf + o)  = pv;
        *(float2*)(sf + o)  = sv;
        *(float2*)(sf2 + o) = sv;
    }
}

extern "C" void kernel_launch(void* const* d_in, const int* in_sizes, int n_in,
                              void* d_out, int out_size, void* d_ws, size_t ws_size,
                              hipStream_t stream) {
    const float* k_inp   = (const float*)d_in[2];
    const float* v_inp   = (const float*)d_in[3];
    const float* slots_mu= (const float*)d_in[4];
    const float* prompts = (const float*)d_in[5];
    const float* Wq      = (const float*)d_in[6];
    const float* bq      = (const float*)d_in[7];
    const float* W_ih    = (const float*)d_in[8];
    const float* b_ih    = (const float*)d_in[9];
    const float* W_hh    = (const float*)d_in[10];
    const float* b_hh    = (const float*)d_in[11];
    const float* W1      = (const float*)d_in[12];
    const float* b1      = (const float*)d_in[13];
    const float* W2      = (const float*)d_in[14];
    const float* b2      = (const float*)d_in[15];
    const float* gk      = (const float*)d_in[16];
    const float* bk      = (const float*)d_in[17];
    const float* gv      = (const float*)d_in[18];
    const float* bv      = (const float*)d_in[19];
    const float* gs      = (const float*)d_in[20];
    const float* bs      = (const float*)d_in[21];
    const float* gff     = (const float*)d_in[22];
    const float* bff     = (const float*)d_in[23];

    float* ws = (float*)d_ws;
    float* slots   = ws + 0;
    float* slots2  = ws + 131072;
    float* sbuf    = ws + 262144;
    float* qg      = ws + 393216;
    float* upd     = ws + 524288;
    float* hid     = ws + 655360;
    float* gp      = ws + 786432;     // 524288 -> ends 1310720
    float* C1p     = ws + 1310720;    // 2048
    float* C2p     = ws + 1312768;    // 2048
    float* kmu     = ws + 1314816;    // 65536
    float* krstd   = ws + 1380352;    // 65536
    float* vmu     = ws + 1445888;    // 65536
    float* vrstd   = ws + 1511424;    // 65536
    float* Sp      = ws + 1576960;    // 16384
    float* Mp      = ws + 1593344;    // 16384 -> 1609728
    f4* TWq  = (f4*)(ws + 1609728);   // 262144 floats -> 1871872
    f4* TWih = (f4*)(ws + 1871872);   // 786432 -> 2658304
    f4* TWhh = (f4*)(ws + 2658304);   // 786432 -> 3444736
    f4* TW1  = (f4*)(ws + 3444736);   // 262144 -> 3706880
    f4* TW2  = (f4*)(ws + 3706880);   // 262144 -> 3969024 floats = 15.9 MB

    float* out      = (float*)d_out;
    float* attn_out = out + 131072;
    float* pf       = out + 1179648;
    float* sf       = pf + 33554432;
    float* sf2      = sf + 33554432;
    float* Uwp      = pf;             // 8.4M floats scratch; overwritten by k_features
    __fp16* kh      = (__fp16*)sf;    // 67 MB f16 k; overwritten by k_features at end

    k_pre<<<1024, 256, 0, stream>>>(slots_mu, k_inp, v_inp, slots, kmu, krstd, vmu, vrstd, kh);
    k_wt<<<2304, 256, 0, stream>>>(Wq, W_ih, W_hh, W1, W2, TWq, TWih, TWhh, TW1, TW2);

    for (int it = 0; it < 3; it++){
        int last = (it == 2);
        k_ln_q<<<dim3(8,64), 256, 0, stream>>>(slots, gs, bs, TWq, bq, gk, bk, qg, C1p, C2p);
        k_attn_av<<<dim3(64,16), 256, 0, stream>>>(kh, v_inp, qg, C1p, C2p,
                                                   kmu, krstd, vmu, vrstd,
                                                   Sp, Mp, Uwp, attn_out, last, 16);
        k_upd<<<256, 256, 0, stream>>>(Uwp, Sp, Mp, gv, bv, upd);
        k_gru_mm<<<dim3(32,16), 256, 0, stream>>>(upd, slots, TWih, b_ih, TWhh, b_hh, gp, 16);
        k_gru_ln<<<256, 256, 0, stream>>>(gp, slots, gff, bff, slots2, sbuf);
        k_ffn1<<<dim3(8,16), 256, 0, stream>>>(sbuf, TW1, b1, hid);
        k_ffn2<<<dim3(8,16), 256, 0, stream>>>(hid, TW2, b2, slots2, slots, out, last);
    }

    k_features<<<dim3(128,16), 256, 0, stream>>>(prompts, slots, attn_out, pf, sf, sf2);
}

// Round 11
// 784.028 us; speedup vs baseline: 8.1828x; 8.1828x over previous
//
#include <hip/hip_runtime.h>
#include <math.h>

#define NN 4096
#define DD 512
#define NSL 16
#define SCALE_F 0.044194173824159216f
#define LN_EPS_F 1e-5f
#define ATTN_EPS_F 1e-8f

typedef float4 f4;
typedef __fp16 h2 __attribute__((ext_vector_type(2)));
typedef _Float16 h2f __attribute__((ext_vector_type(2)));

__device__ __forceinline__ float dot4f(f4 a, f4 b){
    return a.x*b.x + a.y*b.y + a.z*b.z + a.w*b.w;
}
__device__ __forceinline__ float fdot2u(unsigned a, unsigned b, float c){
    return __builtin_amdgcn_fdot2(__builtin_bit_cast(h2f, a),
                                  __builtin_bit_cast(h2f, b), c, false);
}
__device__ __forceinline__ unsigned pk(float x, float y){
    return __builtin_bit_cast(unsigned, __builtin_amdgcn_cvt_pkrtz(x, y));
}

// ---- pre: slots bcast + per-row f32 stats of v,k + f16 copy of k ----
__global__ __launch_bounds__(256) void k_pre(const float* __restrict__ mu,
        const float* __restrict__ kin, const float* __restrict__ vin,
        float* __restrict__ slots, float* __restrict__ kmu, float* __restrict__ krstd,
        float* __restrict__ vmu, float* __restrict__ vrstd,
        __fp16* __restrict__ kh){
    int bx = blockIdx.x, t = threadIdx.x;
    if (bx < 128){
        int idx = bx*256 + t;                      // 32768 f4
        ((f4*)slots)[idx] = ((const f4*)mu)[idx & 2047];
    }
    int sub = t & 15;            // lane within row
    int rl  = t >> 4;            // 16 rows per pass
#pragma unroll
    for (int pass = 0; pass < 8; pass++){
        int task = bx*128 + pass*16 + rl;          // 0..131071
        int half = task >> 16;                     // 0: v, 1: k
        int row  = task & 65535;
        const float* src = half ? kin : vin;
        const f4* r4 = (const f4*)(src + (size_t)row*DD);
        uint2* w2 = (uint2*)(kh + (size_t)row*DD);
        float s = 0.f, ss = 0.f;
#pragma unroll
        for (int k2 = 0; k2 < 8; k2++){
            f4 x = r4[sub + k2*16];
            s  += x.x+x.y+x.z+x.w;
            ss += x.x*x.x+x.y*x.y+x.z*x.z+x.w*x.w;
            if (half){
                uint2 o; o.x = pk(x.x, x.y); o.y = pk(x.z, x.w);
                w2[sub + k2*16] = o;
            }
        }
        for (int o = 1; o < 16; o <<= 1){
            s += __shfl_xor(s, o); ss += __shfl_xor(ss, o);
        }
        if (sub == 0){
            float m = s*(1.f/DD);
            float rs = rsqrtf(ss*(1.f/DD) - m*m + LN_EPS_F);
            if (half){ kmu[row] = m; krstd[row] = rs; }
            else     { vmu[row] = m; vrstd[row] = rs; }
        }
    }
}

// ---- transpose-pack weights: TW[kk][c] = f4(W[c][4kk..4kk+3]) ----
__global__ __launch_bounds__(256) void k_wt(const float* __restrict__ Wq,
        const float* __restrict__ Wih, const float* __restrict__ Whh,
        const float* __restrict__ W1, const float* __restrict__ W2,
        f4* __restrict__ TWq, f4* __restrict__ TWih, f4* __restrict__ TWhh,
        f4* __restrict__ TW1, f4* __restrict__ TW2){
    int id = blockIdx.x*256 + threadIdx.x;
    const float* W; f4* TW; int R, local;
    if (id < 65536)      { W = Wq;  TW = TWq;  R = 512;  local = id; }
    else if (id < 262144){ W = Wih; TW = TWih; R = 1536; local = id - 65536; }
    else if (id < 458752){ W = Whh; TW = TWhh; R = 1536; local = id - 262144; }
    else if (id < 524288){ W = W1;  TW = TW1;  R = 512;  local = id - 458752; }
    else                 { W = W2;  TW = TW2;  R = 512;  local = id - 524288; }
    int kk = local / R, c = local - kk*R;
    TW[local] = ((const f4*)W)[(size_t)c*128 + kk];
}

// ---- fused LN(slots) + q-projection (coalesced TWq) ----
__global__ __launch_bounds__(256) void k_ln_q(const float* __restrict__ slots,
        const float* __restrict__ gs, const float* __restrict__ bs,
        const f4* __restrict__ TWq, const float* __restrict__ bq,
        const float* __restrict__ gk, const float* __restrict__ bk,
        float* __restrict__ qg, float* __restrict__ C1p, float* __restrict__ C2p){
    __shared__ __align__(16) float rowL[4*DD];
    int lane = threadIdx.x & 63, wv = threadIdx.x >> 6;
    int m = blockIdx.y*4 + wv;
    int c = blockIdx.x*64 + lane;
    const f4* r4 = (const f4*)(slots + (size_t)m*DD);
    f4 v0 = r4[lane*2], v1 = r4[lane*2+1];
    float s  = v0.x+v0.y+v0.z+v0.w + v1.x+v1.y+v1.z+v1.w;
    float ss = v0.x*v0.x+v0.y*v0.y+v0.z*v0.z+v0.w*v0.w
             + v1.x*v1.x+v1.y*v1.y+v1.z*v1.z+v1.w*v1.w;
    for (int o = 32; o; o >>= 1){ s += __shfl_down(s,o); ss += __shfl_down(ss,o); }
    s = __shfl(s,0); ss = __shfl(ss,0);
    float mu = s*(1.f/DD);
    float rstd = rsqrtf(ss*(1.f/DD) - mu*mu + LN_EPS_F);
    const f4* g4 = (const f4*)gs; const f4* b4 = (const f4*)bs;
    f4 g0 = g4[lane*2], g1 = g4[lane*2+1], c0 = b4[lane*2], c1 = b4[lane*2+1];
    f4 o0, o1;
    o0.x=(v0.x-mu)*rstd*g0.x+c0.x; o0.y=(v0.y-mu)*rstd*g0.y+c0.y;
    o0.z=(v0.z-mu)*rstd*g0.z+c0.z; o0.w=(v0.w-mu)*rstd*g0.w+c0.w;
    o1.x=(v1.x-mu)*rstd*g1.x+c1.x; o1.y=(v1.y-mu)*rstd*g1.y+c1.y;
    o1.z=(v1.z-mu)*rstd*g1.z+c1.z; o1.w=(v1.w-mu)*rstd*g1.w+c1.w;
    f4* rw = (f4*)(rowL + wv*DD);
    rw[lane*2] = o0; rw[lane*2+1] = o1;
    __syncthreads();
    float acc = 0.f;
    for (int kk = 0; kk < 128; kk++)
        acc += dot4f(rw[kk], TWq[(size_t)kk*512 + c]);
    float q0 = acc + bq[c];
    float qg0 = q0 * gk[c];
    qg[(size_t)m*DD + c] = qg0;
    float r1 = qg0, r2 = q0 * bk[c];
    for (int o = 32; o; o >>= 1){ r1 += __shfl_down(r1,o); r2 += __shfl_down(r2,o); }
    if (lane == 0){
        C1p[blockIdx.x*256 + m] = r1;
        C2p[blockIdx.x*256 + m] = r2;
    }
}

// ---- fused QK^T + inverted softmax + AV partial (f16 k, f32 v) ----
// grid (64 chunks of 64 j, 16 b) = 1024 blocks.
__global__ __launch_bounds__(256, 4) void k_attn_av(const __fp16* __restrict__ kh,
        const float* __restrict__ vin, const float* __restrict__ qg,
        const float* __restrict__ C1p, const float* __restrict__ C2p,
        const float* __restrict__ kmu, const float* __restrict__ krstd,
        const float* __restrict__ vmu, const float* __restrict__ vrstd,
        float* __restrict__ Sp, float* __restrict__ Mp, float* __restrict__ Uwp,
        float* __restrict__ attn_out, int last){
    __shared__ __align__(16) uint4 qhL[1024];      // 16 KB packed f16 q
    __shared__ __align__(16) float wL[64*20];      // 5 KB
    __shared__ float c1s[NSL], c2s[NSL];
    __shared__ float spL[4][NSL], mpL[4][NSL];
    int chunk = blockIdx.x, b = blockIdx.y;
    int t = threadIdx.x, lane = t & 63, wv = t >> 6;
    int r = lane & 15, qq = lane >> 4;

    const f4* qgg = (const f4*)(qg + (size_t)b*NSL*DD);
    for (int e = t; e < 1024; e += 256){
        int dd = e >> 3, p = e & 7;
        f4 qa = qgg[(size_t)(2*p)*128 + dd];
        f4 qb = qgg[(size_t)(2*p+1)*128 + dd];
        uint4 u;
        u.x = pk(qa.x, qa.y);
        u.y = pk(qb.x, qb.y);
        u.z = pk(qa.z, qa.w);
        u.w = pk(qb.z, qb.w);
        qhL[e] = u;
    }
    if (t < NSL){
        float c1 = 0.f, c2 = 0.f;
#pragma unroll
        for (int k = 0; k < 8; k++){
            c1 += C1p[k*256 + b*NSL + t];
            c2 += C2p[k*256 + b*NSL + t];
        }
        c1s[t] = c1; c2s[t] = c2;
    }
    __syncthreads();

    // ---- QK: thread owns quarter qq of row j (f16 k) ----
    int j = chunk*64 + wv*16 + r;
    const uint4* kr = (const uint4*)(kh + ((size_t)b*NN + j)*DD) + qq*16;
    float a[NSL];
#pragma unroll
    for (int i = 0; i < NSL; i++) a[i] = 0.f;
    uint4 kb = kr[0];
    for (int e = 0; e < 16; e++){
        uint4 nk;
        if (e < 15) nk = kr[e+1];
        int dd0 = qq*32 + e*2;
#pragma unroll
        for (int p = 0; p < 8; p++){
            uint4 u = qhL[dd0*8 + p];
            a[2*p]   = fdot2u(kb.x, u.x, a[2*p]);
            a[2*p+1] = fdot2u(kb.x, u.y, a[2*p+1]);
            a[2*p]   = fdot2u(kb.y, u.z, a[2*p]);
            a[2*p+1] = fdot2u(kb.y, u.w, a[2*p+1]);
            uint4 u2 = qhL[(dd0+1)*8 + p];
            a[2*p]   = fdot2u(kb.z, u2.x, a[2*p]);
            a[2*p+1] = fdot2u(kb.z, u2.y, a[2*p+1]);
            a[2*p]   = fdot2u(kb.w, u2.z, a[2*p]);
            a[2*p+1] = fdot2u(kb.w, u2.w, a[2*p+1]);
        }
        kb = nk;
    }
#pragma unroll
    for (int i = 0; i < NSL; i++){
        a[i] += __shfl_xor(a[i], 16);
        a[i] += __shfl_xor(a[i], 32);
    }
    float mu = kmu[(size_t)b*NN + j];
    float rstd = krstd[(size_t)b*NN + j];
    float mx = -1e30f;
#pragma unroll
    for (int i = 0; i < NSL; i++){
        a[i] = SCALE_F*(rstd*(a[i] - mu*c1s[i]) + c2s[i]);
        mx = fmaxf(mx, a[i]);
    }
    float se = 0.f;
#pragma unroll
    for (int i = 0; i < NSL; i++){ a[i] = __expf(a[i]-mx); se += a[i]; }
    float inv = 1.f/se;
    float rv = vrstd[(size_t)b*NN + j];
    float vm = vmu[(size_t)b*NN + j];
#pragma unroll
    for (int i = 0; i < NSL; i++) a[i] = a[i]*inv + ATTN_EPS_F;
#pragma unroll
    for (int i = 0; i < NSL; i++){
        float r1 = a[i], r2 = a[i]*rv*vm;
        for (int o = 1; o < 16; o <<= 1){ r1 += __shfl_xor(r1,o); r2 += __shfl_xor(r2,o); }
        if (lane == 0){ spL[wv][i] = r1; mpL[wv][i] = r2; }
    }
    if (qq == 0){
        int jl = wv*16 + r;
#pragma unroll
        for (int i = 0; i < NSL; i++) wL[jl*20 + i] = a[i]*rv;
        if (last){
#pragma unroll
            for (int i = 0; i < NSL; i++)
                attn_out[((size_t)b*NSL + i)*NN + j] = a[i];
        }
    }
    __syncthreads();

    if (t < NSL)
        Sp[((size_t)b*NSL + t)*64 + chunk] = spL[0][t]+spL[1][t]+spL[2][t]+spL[3][t];
    else if (t < 2*NSL){
        int i = t - NSL;
        Mp[((size_t)b*NSL + i)*64 + chunk] = mpL[0][i]+mpL[1][i]+mpL[2][i]+mpL[3][i];
    }

    // ---- AV partial over this chunk's 64 j (f32 v) ----
    f4 ax[4], ay[4];
#pragma unroll
    for (int g2 = 0; g2 < 4; g2++){ ax[g2] = f4{0,0,0,0}; ay[g2] = f4{0,0,0,0}; }
    const float2* v2 = (const float2*)(vin + ((size_t)b*NN + (size_t)chunk*64)*DD);
#pragma unroll 2
    for (int jj = 0; jj < 64; jj++){
        float2 vv = v2[(size_t)jj*256 + t];
        const f4* wl4 = (const f4*)(wL + jj*20);
#pragma unroll
        for (int g2 = 0; g2 < 4; g2++){
            f4 wq = wl4[g2];
            ax[g2].x += wq.x*vv.x; ax[g2].y += wq.y*vv.x; ax[g2].z += wq.z*vv.x; ax[g2].w += wq.w*vv.x;
            ay[g2].x += wq.x*vv.y; ay[g2].y += wq.y*vv.y; ay[g2].z += wq.z*vv.y; ay[g2].w += wq.w*vv.y;
        }
    }
#pragma unroll
    for (int g2 = 0; g2 < 4; g2++){
        const float* px = (const float*)&ax[g2];
        const float* py = (const float*)&ay[g2];
#pragma unroll
        for (int c4 = 0; c4 < 4; c4++){
            int i = g2*4 + c4;
            float2 o2; o2.x = px[c4]; o2.y = py[c4];
            *(float2*)(Uwp + (((size_t)(b*NSL + i))*64 + chunk)*DD + 2*t) = o2;
        }
    }
}

// ---- updates = gv*(sum Uwp - M)/S + bv  (block = row m) ----
__global__ __launch_bounds__(256) void k_upd(const float* __restrict__ Uwp,
        const float* __restrict__ Sp, const float* __restrict__ Mp,
        const float* __restrict__ gv, const float* __restrict__ bv,
        float* __restrict__ upd){
    __shared__ float sm[2];
    int m = blockIdx.x, t = threadIdx.x;
    if (t < 128){
        float val = (t < 64) ? Sp[(size_t)m*64 + (t&63)] : Mp[(size_t)m*64 + (t&63)];
        for (int o = 1; o < 64; o <<= 1) val += __shfl_xor(val, o);
        if (t == 0)  sm[0] = val;
        if (t == 64) sm[1] = val;
    }
    __syncthreads();
    float Sv = sm[0], Mv = sm[1];
    float rS = 1.f/Sv;
    float2 acc; acc.x = 0.f; acc.y = 0.f;
    const float* base = Uwp + (size_t)m*64*DD + 2*t;
#pragma unroll 8
    for (int ch = 0; ch < 64; ch++){
        float2 u = *(const float2*)(base + (size_t)ch*DD);
        acc.x += u.x; acc.y += u.y;
    }
    float2 gvv = ((const float2*)gv)[t];
    float2 bvv = ((const float2*)bv)[t];
    float2 o2;
    o2.x = gvv.x*(acc.x - Mv)*rS + bvv.x;
    o2.y = gvv.y*(acc.y - Mv)*rS + bvv.y;
    *(float2*)(upd + (size_t)m*DD + 2*t) = o2;
}

// ---- GRU gate matmuls, split-K x2: grid (32 cc, 16 mg, 2 ks) ----
__global__ __launch_bounds__(256) void k_gru_mm(const float* __restrict__ x, const float* __restrict__ h,
        const f4* __restrict__ TWih, const float* __restrict__ bih,
        const f4* __restrict__ TWhh, const float* __restrict__ bhh,
        float* __restrict__ gpA, float* __restrict__ gpB){
    int lane = threadIdx.x & 63, wv = threadIdx.x >> 6;
    int c = blockIdx.x*64 + lane;                 // 0..2047
    int m0 = blockIdx.y*16 + wv*4;
    int ks = blockIdx.z;                          // K half
    int k0 = ks*64, k1 = k0 + 64;
    float* gp = ks ? gpB : gpA;
    int type = c >> 9;
    const f4* x4 = (const f4*)x;
    const f4* h4 = (const f4*)h;
    float acc[4] = {0,0,0,0};
    float bias;
    if (type <= 1){
        for (int kk = k0; kk < k1; kk++){
            f4 aa = TWih[(size_t)kk*1536 + c];
            f4 bb = TWhh[(size_t)kk*1536 + c];
#pragma unroll
            for (int mm = 0; mm < 4; mm++)
                acc[mm] += dot4f(aa, x4[(size_t)(m0+mm)*128+kk]) + dot4f(bb, h4[(size_t)(m0+mm)*128+kk]);
        }
        bias = bih[c] + bhh[c];
    } else if (type == 2){
        for (int kk = k0; kk < k1; kk++){
            f4 aa = TWih[(size_t)kk*1536 + c];
#pragma unroll
            for (int mm = 0; mm < 4; mm++)
                acc[mm] += dot4f(aa, x4[(size_t)(m0+mm)*128+kk]);
        }
        bias = bih[c];
    } else {
        int cr = c - 512;                          // rows 1024..1535 of Whh
        for (int kk = k0; kk < k1; kk++){
            f4 aa = TWhh[(size_t)kk*1536 + cr];
#pragma unroll
            for (int mm = 0; mm < 4; mm++)
                acc[mm] += dot4f(aa, h4[(size_t)(m0+mm)*128+kk]);
        }
        bias = bhh[cr];
    }
    float bout = ks ? 0.f : bias;
#pragma unroll
    for (int mm = 0; mm < 4; mm++)
        gp[(size_t)(m0+mm)*2048 + c] = acc[mm] + bout;
}

// ---- GRU elementwise + LN(gff,bff) fused; sums the two K-halves ----
__global__ __launch_bounds__(256) void k_gru_ln(const float* __restrict__ gpA,
        const float* __restrict__ gpB,
        const float* __restrict__ h, const float* __restrict__ gff, const float* __restrict__ bff,
        float* __restrict__ slots2, float* __restrict__ sbuf){
    __shared__ float sm[8];
    int m = blockIdx.x, t = threadIdx.x, lane = t & 63, wv = t >> 6;
    const float* g0 = gpA + (size_t)m*2048;
    const float* g1 = gpB + (size_t)m*2048;
    float2 rp, zp, nx, nh;
    {
        float2 a0 = *(const float2*)(g0 + 2*t),        a1 = *(const float2*)(g1 + 2*t);
        rp.x = a0.x + a1.x; rp.y = a0.y + a1.y;
        float2 b0 = *(const float2*)(g0 + 512 + 2*t),  b1 = *(const float2*)(g1 + 512 + 2*t);
        zp.x = b0.x + b1.x; zp.y = b0.y + b1.y;
        float2 c0 = *(const float2*)(g0 + 1024 + 2*t), c1 = *(const float2*)(g1 + 1024 + 2*t);
        nx.x = c0.x + c1.x; nx.y = c0.y + c1.y;
        float2 d0 = *(const float2*)(g0 + 1536 + 2*t), d1 = *(const float2*)(g1 + 1536 + 2*t);
        nh.x = d0.x + d1.x; nh.y = d0.y + d1.y;
    }
    float2 hh = *(const float2*)(h + (size_t)m*DD + 2*t);
    float2 s2;
    {
        float r = 1.f/(1.f + __expf(-rp.x));
        float z = 1.f/(1.f + __expf(-zp.x));
        float n = tanhf(nx.x + r*nh.x);
        s2.x = (1.f - z)*n + z*hh.x;
        r = 1.f/(1.f + __expf(-rp.y));
        z = 1.f/(1.f + __expf(-zp.y));
        n = tanhf(nx.y + r*nh.y);
        s2.y = (1.f - z)*n + z*hh.y;
    }
    *(float2*)(slots2 + (size_t)m*DD + 2*t) = s2;
    float s = s2.x + s2.y;
    float ss = s2.x*s2.x + s2.y*s2.y;
    for (int o = 32; o; o >>= 1){ s += __shfl_down(s,o); ss += __shfl_down(ss,o); }
    if (lane == 0){ sm[wv] = s; sm[4+wv] = ss; }
    __syncthreads();
    float S = sm[0]+sm[1]+sm[2]+sm[3];
    float SS = sm[4]+sm[5]+sm[6]+sm[7];
    float mu = S*(1.f/DD);
    float rstd = rsqrtf(SS*(1.f/DD) - mu*mu + LN_EPS_F);
    float2 gg = *(const float2*)(gff + 2*t);
    float2 bb = *(const float2*)(bff + 2*t);
    float2 o2;
    o2.x = (s2.x-mu)*rstd*gg.x + bb.x;
    o2.y = (s2.y-mu)*rstd*gg.y + bb.y;
    *(float2*)(sbuf + (size_t)m*DD + 2*t) = o2;
}

// ---- FFN1: wave-per-row, grid (8, 64) = 512 blocks ----
__global__ __launch_bounds__(256) void k_ffn1(const float* __restrict__ a, const f4* __restrict__ TW1,
                                              const float* __restrict__ b1, float* __restrict__ hid){
    int lane = threadIdx.x & 63, wv = threadIdx.x >> 6;
    int c = blockIdx.x*64 + lane;
    int m = blockIdx.y*4 + wv;
    const f4* a4 = (const f4*)(a + (size_t)m*DD);
    float acc = 0.f;
    for (int kk = 0; kk < 128; kk++)
        acc += dot4f(a4[kk], TW1[(size_t)kk*512 + c]);
    hid[(size_t)m*DD + c] = fmaxf(acc + b1[c], 0.f);
}

// ---- FFN2: wave-per-row, grid (8, 64) = 512 blocks ----
__global__ __launch_bounds__(256) void k_ffn2(const float* __restrict__ hid, const f4* __restrict__ TW2,
                                              const float* __restrict__ b2, const float* __restrict__ slots2,
                                              float* __restrict__ slots, float* __restrict__ out_slots, int last){
    int lane = threadIdx.x & 63, wv = threadIdx.x >> 6;
    int d = blockIdx.x*64 + lane;
    int m = blockIdx.y*4 + wv;
    const f4* h4 = (const f4*)(hid + (size_t)m*DD);
    float acc = 0.f;
    for (int kk = 0; kk < 128; kk++)
        acc += dot4f(h4[kk], TW2[(size_t)kk*512 + d]);
    float v0 = slots2[(size_t)m*DD + d] + acc + b2[d];
    slots[(size_t)m*DD + d] = v0;
    if (last) out_slots[(size_t)m*DD + d] = v0;
}

// ---- features ----
__global__ __launch_bounds__(256) void k_features(const float* __restrict__ prompts, const float* __restrict__ slots,
        const float* __restrict__ attn, float* __restrict__ pf, float* __restrict__ sf, float* __restrict__ sf2){
    int b = blockIdx.y;
    int pbase = blockIdx.x*32;
    int t = threadIdx.x;
    __shared__ float al[NSL][33];
    for (int idx = t; idx < NSL*32; idx += 256){
        int i = idx >> 5, pp = idx & 31;
        al[i][pp] = attn[((size_t)b*NSL + i)*NN + pbase + pp];
    }
    float2 pr[NSL], sl[NSL];
    const float2* p2 = (const float2*)prompts;
    const float2* s2 = (const float2*)(slots + (size_t)b*NSL*DD);
#pragma unroll
    for (int i = 0; i < NSL; i++){ pr[i] = p2[i*256+t]; sl[i] = s2[i*256+t]; }
    __syncthreads();
    for (int pp = 0; pp < 32; pp++){
        float a0=0.f, a1=0.f, c0=0.f, c1=0.f;
#pragma unroll
        for (int i = 0; i < NSL; i++){
            float a = al[i][pp];
            a0 += a*pr[i].x; a1 += a*pr[i].y;
            c0 += a*sl[i].x; c1 += a*sl[i].y;
        }
        size_t o = ((size_t)b*NN + pbase + pp)*DD + 2*t;
        float2 pv; pv.x=a0; pv.y=a1;
        float2 sv; sv.x=c0; sv.y=c1;
        *(float2*)(pf + o)  = pv;
        *(float2*)(sf + o)  = sv;
        *(float2*)(sf2 + o) = sv;
    }
}

extern "C" void kernel_launch(void* const* d_in, const int* in_sizes, int n_in,
                              void* d_out, int out_size, void* d_ws, size_t ws_size,
                              hipStream_t stream) {
    const float* k_inp   = (const float*)d_in[2];
    const float* v_inp   = (const float*)d_in[3];
    const float* slots_mu= (const float*)d_in[4];
    const float* prompts = (const float*)d_in[5];
    const float* Wq      = (const float*)d_in[6];
    const float* bq      = (const float*)d_in[7];
    const float* W_ih    = (const float*)d_in[8];
    const float* b_ih    = (const float*)d_in[9];
    const float* W_hh    = (const float*)d_in[10];
    const float* b_hh    = (const float*)d_in[11];
    const float* W1      = (const float*)d_in[12];
    const float* b1      = (const float*)d_in[13];
    const float* W2      = (const float*)d_in[14];
    const float* b2      = (const float*)d_in[15];
    const float* gk      = (const float*)d_in[16];
    const float* bk      = (const float*)d_in[17];
    const float* gv      = (const float*)d_in[18];
    const float* bv      = (const float*)d_in[19];
    const float* gs      = (const float*)d_in[20];
    const float* bs      = (const float*)d_in[21];
    const float* gff     = (const float*)d_in[22];
    const float* bff     = (const float*)d_in[23];

    float* ws = (float*)d_ws;
    float* slots   = ws + 0;
    float* slots2  = ws + 131072;
    float* sbuf    = ws + 262144;
    float* qg      = ws + 393216;
    float* upd     = ws + 524288;
    float* hid     = ws + 655360;
    float* gp      = ws + 786432;     // 524288 -> ends 1310720
    float* C1p     = ws + 1310720;    // 2048
    float* C2p     = ws + 1312768;    // 2048
    float* kmu     = ws + 1314816;    // 65536
    float* krstd   = ws + 1380352;    // 65536
    float* vmu     = ws + 1445888;    // 65536
    float* vrstd   = ws + 1511424;    // 65536
    float* Sp      = ws + 1576960;    // 16384
    float* Mp      = ws + 1593344;    // 16384 -> 1609728
    f4* TWq  = (f4*)(ws + 1609728);   // 262144 floats -> 1871872
    f4* TWih = (f4*)(ws + 1871872);   // 786432 -> 2658304
    f4* TWhh = (f4*)(ws + 2658304);   // 786432 -> 3444736
    f4* TW1  = (f4*)(ws + 3444736);   // 262144 -> 3706880
    f4* TW2  = (f4*)(ws + 3706880);   // 262144 -> 3969024 floats = 15.9 MB

    float* out      = (float*)d_out;
    float* attn_out = out + 131072;
    float* pf       = out + 1179648;
    float* sf       = pf + 33554432;
    float* sf2      = sf + 33554432;
    float* Uwp      = pf;                    // 8.4M floats scratch in pf region
    float* gpB      = pf + 16777216;         // 0.5M floats scratch in pf region
    __fp16* kh      = (__fp16*)sf;           // 67 MB f16 k in sf region
    // all pf/sf scratch is consumed before k_features overwrites those regions

    k_pre<<<1024, 256, 0, stream>>>(slots_mu, k_inp, v_inp, slots, kmu, krstd, vmu, vrstd, kh);
    k_wt<<<2304, 256, 0, stream>>>(Wq, W_ih, W_hh, W1, W2, TWq, TWih, TWhh, TW1, TW2);

    for (int it = 0; it < 3; it++){
        int last = (it == 2);
        k_ln_q<<<dim3(8,64), 256, 0, stream>>>(slots, gs, bs, TWq, bq, gk, bk, qg, C1p, C2p);
        k_attn_av<<<dim3(64,16), 256, 0, stream>>>(kh, v_inp, qg, C1p, C2p,
                                                   kmu, krstd, vmu, vrstd,
                                                   Sp, Mp, Uwp, attn_out, last);
        k_upd<<<256, 256, 0, stream>>>(Uwp, Sp, Mp, gv, bv, upd);
        k_gru_mm<<<dim3(32,16,2), 256, 0, stream>>>(upd, slots, TWih, b_ih, TWhh, b_hh, gp, gpB);
        k_gru_ln<<<256, 256, 0, stream>>>(gp, gpB, slots, gff, bff, slots2, sbuf);
        k_ffn1<<<dim3(8,64), 256, 0, stream>>>(sbuf, TW1, b1, hid);
        k_ffn2<<<dim3(8,64), 256, 0, stream>>>(hid, TW2, b2, slots2, slots, out, last);
    }

    k_features<<<dim3(128,16), 256, 0, stream>>>(prompts, slots, attn_out, pf, sf, sf2);
}

// Round 12
// 744.448 us; speedup vs baseline: 8.6178x; 1.0532x over previous
//
#include <hip/hip_runtime.h>
#include <math.h>

#define NN 4096
#define DD 512
#define NSL 16
#define SCALE_F 0.044194173824159216f
#define LN_EPS_F 1e-5f
#define ATTN_EPS_F 1e-8f

typedef float4 f4;
typedef __fp16 h2 __attribute__((ext_vector_type(2)));
typedef _Float16 h2f __attribute__((ext_vector_type(2)));

__device__ __forceinline__ float dot4f(f4 a, f4 b){
    return a.x*b.x + a.y*b.y + a.z*b.z + a.w*b.w;
}
__device__ __forceinline__ float fdot2u(unsigned a, unsigned b, float c){
    return __builtin_amdgcn_fdot2(__builtin_bit_cast(h2f, a),
                                  __builtin_bit_cast(h2f, b), c, false);
}
__device__ __forceinline__ unsigned pk(float x, float y){
    return __builtin_bit_cast(unsigned, __builtin_amdgcn_cvt_pkrtz(x, y));
}

// ---- pre: slots bcast (f32 + f16) + per-row f32 stats of v,k + f16 copy of k ----
__global__ __launch_bounds__(256) void k_pre(const float* __restrict__ mu,
        const float* __restrict__ kin, const float* __restrict__ vin,
        float* __restrict__ slots, __fp16* __restrict__ slotsh,
        float* __restrict__ kmu, float* __restrict__ krstd,
        float* __restrict__ vmu, float* __restrict__ vrstd,
        __fp16* __restrict__ kh){
    int bx = blockIdx.x, t = threadIdx.x;
    if (bx < 128){
        int idx = bx*256 + t;                      // 32768 f4
        f4 v = ((const f4*)mu)[idx & 2047];
        ((f4*)slots)[idx] = v;
        uint2 o; o.x = pk(v.x, v.y); o.y = pk(v.z, v.w);
        ((uint2*)slotsh)[idx] = o;
    }
    int sub = t & 15;
    int rl  = t >> 4;
#pragma unroll
    for (int pass = 0; pass < 8; pass++){
        int task = bx*128 + pass*16 + rl;          // 0..131071
        int half = task >> 16;                     // 0: v, 1: k
        int row  = task & 65535;
        const float* src = half ? kin : vin;
        const f4* r4 = (const f4*)(src + (size_t)row*DD);
        uint2* w2 = (uint2*)(kh + (size_t)row*DD);
        float s = 0.f, ss = 0.f;
#pragma unroll
        for (int k2 = 0; k2 < 8; k2++){
            f4 x = r4[sub + k2*16];
            s  += x.x+x.y+x.z+x.w;
            ss += x.x*x.x+x.y*x.y+x.z*x.z+x.w*x.w;
            if (half){
                uint2 o; o.x = pk(x.x, x.y); o.y = pk(x.z, x.w);
                w2[sub + k2*16] = o;
            }
        }
        for (int o = 1; o < 16; o <<= 1){
            s += __shfl_xor(s, o); ss += __shfl_xor(ss, o);
        }
        if (sub == 0){
            float m = s*(1.f/DD);
            float rs = rsqrtf(ss*(1.f/DD) - m*m + LN_EPS_F);
            if (half){ kmu[row] = m; krstd[row] = rs; }
            else     { vmu[row] = m; vrstd[row] = rs; }
        }
    }
}

// ---- transpose-pack weights to f16: TWh[kk][c] = pk4(W[c][4kk..4kk+3]) ----
__global__ __launch_bounds__(256) void k_wt(const float* __restrict__ Wq,
        const float* __restrict__ Wih, const float* __restrict__ Whh,
        const float* __restrict__ W1, const float* __restrict__ W2,
        uint2* __restrict__ TWq, uint2* __restrict__ TWih, uint2* __restrict__ TWhh,
        uint2* __restrict__ TW1, uint2* __restrict__ TW2){
    int id = blockIdx.x*256 + threadIdx.x;
    const float* W; uint2* TW; int R, local;
    if (id < 65536)      { W = Wq;  TW = TWq;  R = 512;  local = id; }
    else if (id < 262144){ W = Wih; TW = TWih; R = 1536; local = id - 65536; }
    else if (id < 458752){ W = Whh; TW = TWhh; R = 1536; local = id - 262144; }
    else if (id < 524288){ W = W1;  TW = TW1;  R = 512;  local = id - 458752; }
    else                 { W = W2;  TW = TW2;  R = 512;  local = id - 524288; }
    int kk = local / R, c = local - kk*R;
    f4 w = ((const f4*)W)[(size_t)c*128 + kk];
    uint2 o; o.x = pk(w.x, w.y); o.y = pk(w.z, w.w);
    TW[local] = o;
}

// ---- fused LN(slots) + q-projection (f16 weights, fdot2) ----
__global__ __launch_bounds__(256) void k_ln_q(const float* __restrict__ slots,
        const float* __restrict__ gs, const float* __restrict__ bs,
        const uint2* __restrict__ TWq, const float* __restrict__ bq,
        const float* __restrict__ gk, const float* __restrict__ bk,
        float* __restrict__ qg, float* __restrict__ C1p, float* __restrict__ C2p){
    __shared__ uint2 rowh[4][128];                // per-wave normalized row, f16
    int lane = threadIdx.x & 63, wv = threadIdx.x >> 6;
    int m = blockIdx.y*4 + wv;
    int c = blockIdx.x*64 + lane;
    const f4* r4 = (const f4*)(slots + (size_t)m*DD);
    f4 v0 = r4[lane*2], v1 = r4[lane*2+1];
    float s  = v0.x+v0.y+v0.z+v0.w + v1.x+v1.y+v1.z+v1.w;
    float ss = v0.x*v0.x+v0.y*v0.y+v0.z*v0.z+v0.w*v0.w
             + v1.x*v1.x+v1.y*v1.y+v1.z*v1.z+v1.w*v1.w;
    for (int o = 32; o; o >>= 1){ s += __shfl_down(s,o); ss += __shfl_down(ss,o); }
    s = __shfl(s,0); ss = __shfl(ss,0);
    float mu = s*(1.f/DD);
    float rstd = rsqrtf(ss*(1.f/DD) - mu*mu + LN_EPS_F);
    const f4* g4 = (const f4*)gs; const f4* b4 = (const f4*)bs;
    f4 g0 = g4[lane*2], g1 = g4[lane*2+1], c0 = b4[lane*2], c1 = b4[lane*2+1];
    f4 o0, o1;
    o0.x=(v0.x-mu)*rstd*g0.x+c0.x; o0.y=(v0.y-mu)*rstd*g0.y+c0.y;
    o0.z=(v0.z-mu)*rstd*g0.z+c0.z; o0.w=(v0.w-mu)*rstd*g0.w+c0.w;
    o1.x=(v1.x-mu)*rstd*g1.x+c1.x; o1.y=(v1.y-mu)*rstd*g1.y+c1.y;
    o1.z=(v1.z-mu)*rstd*g1.z+c1.z; o1.w=(v1.w-mu)*rstd*g1.w+c1.w;
    rowh[wv][lane*2]     = uint2{pk(o0.x,o0.y), pk(o0.z,o0.w)};
    rowh[wv][lane*2 + 1] = uint2{pk(o1.x,o1.y), pk(o1.z,o1.w)};
    __syncthreads();
    float acc = 0.f;
    for (int kk = 0; kk < 128; kk++){
        uint2 q2 = rowh[wv][kk];
        uint2 w2 = TWq[(size_t)kk*512 + c];
        acc = fdot2u(w2.x, q2.x, acc);
        acc = fdot2u(w2.y, q2.y, acc);
    }
    float q0 = acc + bq[c];
    float qg0 = q0 * gk[c];
    qg[(size_t)m*DD + c] = qg0;
    float r1 = qg0, r2 = q0 * bk[c];
    for (int o = 32; o; o >>= 1){ r1 += __shfl_down(r1,o); r2 += __shfl_down(r2,o); }
    if (lane == 0){
        C1p[blockIdx.x*256 + m] = r1;
        C2p[blockIdx.x*256 + m] = r2;
    }
}

// ---- fused QK^T + inverted softmax + AV partial (f16 k, f32 v) ----
__global__ __launch_bounds__(256, 4) void k_attn_av(const __fp16* __restrict__ kh,
        const float* __restrict__ vin, const float* __restrict__ qg,
        const float* __restrict__ C1p, const float* __restrict__ C2p,
        const float* __restrict__ kmu, const float* __restrict__ krstd,
        const float* __restrict__ vmu, const float* __restrict__ vrstd,
        float* __restrict__ Sp, float* __restrict__ Mp, float* __restrict__ Uwp,
        float* __restrict__ attn_out, int last){
    __shared__ __align__(16) uint4 qhL[1024];      // 16 KB packed f16 q
    __shared__ __align__(16) float wL[64*20];      // 5 KB
    __shared__ float c1s[NSL], c2s[NSL];
    __shared__ float spL[4][NSL], mpL[4][NSL];
    int chunk = blockIdx.x, b = blockIdx.y;
    int t = threadIdx.x, lane = t & 63, wv = t >> 6;
    int r = lane & 15, qq = lane >> 4;

    const f4* qgg = (const f4*)(qg + (size_t)b*NSL*DD);
    for (int e = t; e < 1024; e += 256){
        int dd = e >> 3, p = e & 7;
        f4 qa = qgg[(size_t)(2*p)*128 + dd];
        f4 qb = qgg[(size_t)(2*p+1)*128 + dd];
        uint4 u;
        u.x = pk(qa.x, qa.y);
        u.y = pk(qb.x, qb.y);
        u.z = pk(qa.z, qa.w);
        u.w = pk(qb.z, qb.w);
        qhL[e] = u;
    }
    if (t < NSL){
        float c1 = 0.f, c2 = 0.f;
#pragma unroll
        for (int k = 0; k < 8; k++){
            c1 += C1p[k*256 + b*NSL + t];
            c2 += C2p[k*256 + b*NSL + t];
        }
        c1s[t] = c1; c2s[t] = c2;
    }
    __syncthreads();

    int j = chunk*64 + wv*16 + r;
    const uint4* kr = (const uint4*)(kh + ((size_t)b*NN + j)*DD) + qq*16;
    float a[NSL];
#pragma unroll
    for (int i = 0; i < NSL; i++) a[i] = 0.f;
    uint4 kb = kr[0];
    for (int e = 0; e < 16; e++){
        uint4 nk;
        if (e < 15) nk = kr[e+1];
        int dd0 = qq*32 + e*2;
#pragma unroll
        for (int p = 0; p < 8; p++){
            uint4 u = qhL[dd0*8 + p];
            a[2*p]   = fdot2u(kb.x, u.x, a[2*p]);
            a[2*p+1] = fdot2u(kb.x, u.y, a[2*p+1]);
            a[2*p]   = fdot2u(kb.y, u.z, a[2*p]);
            a[2*p+1] = fdot2u(kb.y, u.w, a[2*p+1]);
            uint4 u2 = qhL[(dd0+1)*8 + p];
            a[2*p]   = fdot2u(kb.z, u2.x, a[2*p]);
            a[2*p+1] = fdot2u(kb.z, u2.y, a[2*p+1]);
            a[2*p]   = fdot2u(kb.w, u2.z, a[2*p]);
            a[2*p+1] = fdot2u(kb.w, u2.w, a[2*p+1]);
        }
        kb = nk;
    }
#pragma unroll
    for (int i = 0; i < NSL; i++){
        a[i] += __shfl_xor(a[i], 16);
        a[i] += __shfl_xor(a[i], 32);
    }
    float mu = kmu[(size_t)b*NN + j];
    float rstd = krstd[(size_t)b*NN + j];
    float mx = -1e30f;
#pragma unroll
    for (int i = 0; i < NSL; i++){
        a[i] = SCALE_F*(rstd*(a[i] - mu*c1s[i]) + c2s[i]);
        mx = fmaxf(mx, a[i]);
    }
    float se = 0.f;
#pragma unroll
    for (int i = 0; i < NSL; i++){ a[i] = __expf(a[i]-mx); se += a[i]; }
    float inv = 1.f/se;
    float rv = vrstd[(size_t)b*NN + j];
    float vm = vmu[(size_t)b*NN + j];
#pragma unroll
    for (int i = 0; i < NSL; i++) a[i] = a[i]*inv + ATTN_EPS_F;
#pragma unroll
    for (int i = 0; i < NSL; i++){
        float r1 = a[i], r2 = a[i]*rv*vm;
        for (int o = 1; o < 16; o <<= 1){ r1 += __shfl_xor(r1,o); r2 += __shfl_xor(r2,o); }
        if (lane == 0){ spL[wv][i] = r1; mpL[wv][i] = r2; }
    }
    if (qq == 0){
        int jl = wv*16 + r;
#pragma unroll
        for (int i = 0; i < NSL; i++) wL[jl*20 + i] = a[i]*rv;
        if (last){
#pragma unroll
            for (int i = 0; i < NSL; i++)
                attn_out[((size_t)b*NSL + i)*NN + j] = a[i];
        }
    }
    __syncthreads();

    if (t < NSL)
        Sp[((size_t)b*NSL + t)*64 + chunk] = spL[0][t]+spL[1][t]+spL[2][t]+spL[3][t];
    else if (t < 2*NSL){
        int i = t - NSL;
        Mp[((size_t)b*NSL + i)*64 + chunk] = mpL[0][i]+mpL[1][i]+mpL[2][i]+mpL[3][i];
    }

    f4 ax[4], ay[4];
#pragma unroll
    for (int g2 = 0; g2 < 4; g2++){ ax[g2] = f4{0,0,0,0}; ay[g2] = f4{0,0,0,0}; }
    const float2* v2 = (const float2*)(vin + ((size_t)b*NN + (size_t)chunk*64)*DD);
#pragma unroll 2
    for (int jj = 0; jj < 64; jj++){
        float2 vv = v2[(size_t)jj*256 + t];
        const f4* wl4 = (const f4*)(wL + jj*20);
#pragma unroll
        for (int g2 = 0; g2 < 4; g2++){
            f4 wq = wl4[g2];
            ax[g2].x += wq.x*vv.x; ax[g2].y += wq.y*vv.x; ax[g2].z += wq.z*vv.x; ax[g2].w += wq.w*vv.x;
            ay[g2].x += wq.x*vv.y; ay[g2].y += wq.y*vv.y; ay[g2].z += wq.z*vv.y; ay[g2].w += wq.w*vv.y;
        }
    }
#pragma unroll
    for (int g2 = 0; g2 < 4; g2++){
        const float* px = (const float*)&ax[g2];
        const float* py = (const float*)&ay[g2];
#pragma unroll
        for (int c4 = 0; c4 < 4; c4++){
            int i = g2*4 + c4;
            float2 o2; o2.x = px[c4]; o2.y = py[c4];
            *(float2*)(Uwp + (((size_t)(b*NSL + i))*64 + chunk)*DD + 2*t) = o2;
        }
    }
}

// ---- updates = gv*(sum Uwp - M)/S + bv -> updh (f16)  (block = row m) ----
__global__ __launch_bounds__(256) void k_upd(const float* __restrict__ Uwp,
        const float* __restrict__ Sp, const float* __restrict__ Mp,
        const float* __restrict__ gv, const float* __restrict__ bv,
        __fp16* __restrict__ updh){
    __shared__ float sm[2];
    int m = blockIdx.x, t = threadIdx.x;
    if (t < 128){
        float val = (t < 64) ? Sp[(size_t)m*64 + (t&63)] : Mp[(size_t)m*64 + (t&63)];
        for (int o = 1; o < 64; o <<= 1) val += __shfl_xor(val, o);
        if (t == 0)  sm[0] = val;
        if (t == 64) sm[1] = val;
    }
    __syncthreads();
    float Sv = sm[0], Mv = sm[1];
    float rS = 1.f/Sv;
    float2 acc; acc.x = 0.f; acc.y = 0.f;
    const float* base = Uwp + (size_t)m*64*DD + 2*t;
#pragma unroll 8
    for (int ch = 0; ch < 64; ch++){
        float2 u = *(const float2*)(base + (size_t)ch*DD);
        acc.x += u.x; acc.y += u.y;
    }
    float2 gvv = ((const float2*)gv)[t];
    float2 bvv = ((const float2*)bv)[t];
    float ox = gvv.x*(acc.x - Mv)*rS + bvv.x;
    float oy = gvv.y*(acc.y - Mv)*rS + bvv.y;
    ((unsigned*)updh)[(size_t)m*256 + t] = pk(ox, oy);
}

// ---- GRU gate matmuls, f16 + split-K x2: grid (32 cc, 16 mg, 2 ks) ----
__global__ __launch_bounds__(256) void k_gru_mm(const __fp16* __restrict__ xh, const __fp16* __restrict__ hh,
        const uint2* __restrict__ TWih, const float* __restrict__ bih,
        const uint2* __restrict__ TWhh, const float* __restrict__ bhh,
        float* __restrict__ gpA, float* __restrict__ gpB){
    int lane = threadIdx.x & 63, wv = threadIdx.x >> 6;
    int c = blockIdx.x*64 + lane;                 // 0..2047
    int m0 = blockIdx.y*16 + wv*4;
    int ks = blockIdx.z;
    int k0 = ks*64, k1 = k0 + 64;
    float* gp = ks ? gpB : gpA;
    int type = c >> 9;
    const uint2* x2 = (const uint2*)xh;           // [row][kk] 4 dims per uint2
    const uint2* h2_ = (const uint2*)hh;
    float acc[4] = {0,0,0,0};
    float bias;
    if (type <= 1){
        for (int kk = k0; kk < k1; kk++){
            uint2 wa = TWih[(size_t)kk*1536 + c];
            uint2 wb = TWhh[(size_t)kk*1536 + c];
#pragma unroll
            for (int mm = 0; mm < 4; mm++){
                uint2 xa = x2[(size_t)(m0+mm)*128 + kk];
                uint2 ha = h2_[(size_t)(m0+mm)*128 + kk];
                acc[mm] = fdot2u(wa.x, xa.x, acc[mm]);
                acc[mm] = fdot2u(wa.y, xa.y, acc[mm]);
                acc[mm] = fdot2u(wb.x, ha.x, acc[mm]);
                acc[mm] = fdot2u(wb.y, ha.y, acc[mm]);
            }
        }
        bias = bih[c] + bhh[c];
    } else if (type == 2){
        for (int kk = k0; kk < k1; kk++){
            uint2 wa = TWih[(size_t)kk*1536 + c];
#pragma unroll
            for (int mm = 0; mm < 4; mm++){
                uint2 xa = x2[(size_t)(m0+mm)*128 + kk];
                acc[mm] = fdot2u(wa.x, xa.x, acc[mm]);
                acc[mm] = fdot2u(wa.y, xa.y, acc[mm]);
            }
        }
        bias = bih[c];
    } else {
        int cr = c - 512;
        for (int kk = k0; kk < k1; kk++){
            uint2 wb = TWhh[(size_t)kk*1536 + cr];
#pragma unroll
            for (int mm = 0; mm < 4; mm++){
                uint2 ha = h2_[(size_t)(m0+mm)*128 + kk];
                acc[mm] = fdot2u(wb.x, ha.x, acc[mm]);
                acc[mm] = fdot2u(wb.y, ha.y, acc[mm]);
            }
        }
        bias = bhh[cr];
    }
    float bout = ks ? 0.f : bias;
#pragma unroll
    for (int mm = 0; mm < 4; mm++)
        gp[(size_t)(m0+mm)*2048 + c] = acc[mm] + bout;
}

// ---- tail1: GRU-elem + LN(gff,bff) (redundant per c-block) + FFN1 -> hidh ----
// grid (8, 64); wave = row m. cc==0 also writes slots2 (f32, residual for ffn2).
__global__ __launch_bounds__(256) void k_tail1(const float* __restrict__ gpA,
        const float* __restrict__ gpB, const float* __restrict__ slots,
        const float* __restrict__ gff, const float* __restrict__ bff,
        const uint2* __restrict__ TW1, const float* __restrict__ b1,
        float* __restrict__ slots2, __fp16* __restrict__ hidh){
    __shared__ uint2 rowh[4][128];
    int lane = threadIdx.x & 63, wv = threadIdx.x >> 6;
    int m = blockIdx.y*4 + wv;
    int c = blockIdx.x*64 + lane;
    const f4* g0 = (const f4*)(gpA + (size_t)m*2048);
    const f4* g1 = (const f4*)(gpB + (size_t)m*2048);
    const f4* h4 = (const f4*)(slots + (size_t)m*DD);
    f4 s2v[2];
    float s = 0.f, ss = 0.f;
#pragma unroll
    for (int half = 0; half < 2; half++){
        int e = lane*2 + half;
        f4 rp = g0[e],      zp = g0[128+e],  nx = g0[256+e],  nh = g0[384+e];
        f4 rq = g1[e],      zq = g1[128+e],  ny = g1[256+e],  nz = g1[384+e];
        rp.x+=rq.x; rp.y+=rq.y; rp.z+=rq.z; rp.w+=rq.w;
        zp.x+=zq.x; zp.y+=zq.y; zp.z+=zq.z; zp.w+=zq.w;
        nx.x+=ny.x; nx.y+=ny.y; nx.z+=ny.z; nx.w+=ny.w;
        nh.x+=nz.x; nh.y+=nz.y; nh.z+=nz.z; nh.w+=nz.w;
        f4 hv = h4[e];
        f4 o;
        {
            float r = 1.f/(1.f + __expf(-rp.x));
            float z = 1.f/(1.f + __expf(-zp.x));
            float n = tanhf(nx.x + r*nh.x);
            o.x = (1.f - z)*n + z*hv.x;
            r = 1.f/(1.f + __expf(-rp.y)); z = 1.f/(1.f + __expf(-zp.y));
            n = tanhf(nx.y + r*nh.y);
            o.y = (1.f - z)*n + z*hv.y;
            r = 1.f/(1.f + __expf(-rp.z)); z = 1.f/(1.f + __expf(-zp.z));
            n = tanhf(nx.z + r*nh.z);
            o.z = (1.f - z)*n + z*hv.z;
            r = 1.f/(1.f + __expf(-rp.w)); z = 1.f/(1.f + __expf(-zp.w));
            n = tanhf(nx.w + r*nh.w);
            o.w = (1.f - z)*n + z*hv.w;
        }
        s2v[half] = o;
        s  += o.x+o.y+o.z+o.w;
        ss += o.x*o.x+o.y*o.y+o.z*o.z+o.w*o.w;
        if (blockIdx.x == 0)
            ((f4*)(slots2 + (size_t)m*DD))[e] = o;
    }
    for (int o = 32; o; o >>= 1){ s += __shfl_down(s,o); ss += __shfl_down(ss,o); }
    s = __shfl(s,0); ss = __shfl(ss,0);
    float mu = s*(1.f/DD);
    float rstd = rsqrtf(ss*(1.f/DD) - mu*mu + LN_EPS_F);
    const f4* gg4 = (const f4*)gff; const f4* bb4 = (const f4*)bff;
#pragma unroll
    for (int half = 0; half < 2; half++){
        int e = lane*2 + half;
        f4 gg = gg4[e], bb = bb4[e], o = s2v[half], n;
        n.x = (o.x-mu)*rstd*gg.x + bb.x;
        n.y = (o.y-mu)*rstd*gg.y + bb.y;
        n.z = (o.z-mu)*rstd*gg.z + bb.z;
        n.w = (o.w-mu)*rstd*gg.w + bb.w;
        rowh[wv][e] = uint2{pk(n.x,n.y), pk(n.z,n.w)};
    }
    __syncthreads();
    float acc = 0.f;
    for (int kk = 0; kk < 128; kk++){
        uint2 q2 = rowh[wv][kk];
        uint2 w2 = TW1[(size_t)kk*512 + c];
        acc = fdot2u(w2.x, q2.x, acc);
        acc = fdot2u(w2.y, q2.y, acc);
    }
    float hv = fmaxf(acc + b1[c], 0.f);
    hidh[(size_t)m*DD + c] = (__fp16)hv;
}

// ---- FFN2: f16 hid/W2 + slots2 residual -> slots f32 + slotsh f16 (+out) ----
__global__ __launch_bounds__(256) void k_ffn2(const __fp16* __restrict__ hidh, const uint2* __restrict__ TW2,
                                              const float* __restrict__ b2, const float* __restrict__ slots2,
                                              float* __restrict__ slots, __fp16* __restrict__ slotsh,
                                              float* __restrict__ out_slots, int last){
    int lane = threadIdx.x & 63, wv = threadIdx.x >> 6;
    int d = blockIdx.x*64 + lane;
    int m = blockIdx.y*4 + wv;
    const uint2* h2_ = (const uint2*)(hidh + (size_t)m*DD);
    float acc = 0.f;
    for (int kk = 0; kk < 128; kk++){
        uint2 hh = h2_[kk];
        uint2 w2 = TW2[(size_t)kk*512 + d];
        acc = fdot2u(w2.x, hh.x, acc);
        acc = fdot2u(w2.y, hh.y, acc);
    }
    float v0 = slots2[(size_t)m*DD + d] + acc + b2[d];
    slots[(size_t)m*DD + d] = v0;
    slotsh[(size_t)m*DD + d] = (__fp16)v0;
    if (last) out_slots[(size_t)m*DD + d] = v0;
}

// ---- features ----
__global__ __launch_bounds__(256) void k_features(const float* __restrict__ prompts, const float* __restrict__ slots,
        const float* __restrict__ attn, float* __restrict__ pf, float* __restrict__ sf, float* __restrict__ sf2){
    int b = blockIdx.y;
    int pbase = blockIdx.x*32;
    int t = threadIdx.x;
    __shared__ float al[NSL][33];
    for (int idx = t; idx < NSL*32; idx += 256){
        int i = idx >> 5, pp = idx & 31;
        al[i][pp] = attn[((size_t)b*NSL + i)*NN + pbase + pp];
    }
    float2 pr[NSL], sl[NSL];
    const float2* p2 = (const float2*)prompts;
    const float2* s2 = (const float2*)(slots + (size_t)b*NSL*DD);
#pragma unroll
    for (int i = 0; i < NSL; i++){ pr[i] = p2[i*256+t]; sl[i] = s2[i*256+t]; }
    __syncthreads();
    for (int pp = 0; pp < 32; pp++){
        float a0=0.f, a1=0.f, c0=0.f, c1=0.f;
#pragma unroll
        for (int i = 0; i < NSL; i++){
            float a = al[i][pp];
            a0 += a*pr[i].x; a1 += a*pr[i].y;
            c0 += a*sl[i].x; c1 += a*sl[i].y;
        }
        size_t o = ((size_t)b*NN + pbase + pp)*DD + 2*t;
        float2 pv; pv.x=a0; pv.y=a1;
        float2 sv; sv.x=c0; sv.y=c1;
        *(float2*)(pf + o)  = pv;
        *(float2*)(sf + o)  = sv;
        *(float2*)(sf2 + o) = sv;
    }
}

extern "C" void kernel_launch(void* const* d_in, const int* in_sizes, int n_in,
                              void* d_out, int out_size, void* d_ws, size_t ws_size,
                              hipStream_t stream) {
    const float* k_inp   = (const float*)d_in[2];
    const float* v_inp   = (const float*)d_in[3];
    const float* slots_mu= (const float*)d_in[4];
    const float* prompts = (const float*)d_in[5];
    const float* Wq      = (const float*)d_in[6];
    const float* bq      = (const float*)d_in[7];
    const float* W_ih    = (const float*)d_in[8];
    const float* b_ih    = (const float*)d_in[9];
    const float* W_hh    = (const float*)d_in[10];
    const float* b_hh    = (const float*)d_in[11];
    const float* W1      = (const float*)d_in[12];
    const float* b1      = (const float*)d_in[13];
    const float* W2      = (const float*)d_in[14];
    const float* b2      = (const float*)d_in[15];
    const float* gk      = (const float*)d_in[16];
    const float* bk      = (const float*)d_in[17];
    const float* gv      = (const float*)d_in[18];
    const float* bv      = (const float*)d_in[19];
    const float* gs      = (const float*)d_in[20];
    const float* bs      = (const float*)d_in[21];
    const float* gff     = (const float*)d_in[22];
    const float* bff     = (const float*)d_in[23];

    float* ws = (float*)d_ws;
    float* slots   = ws + 0;           // 131072
    float* slots2  = ws + 131072;      // 131072
    float* qg      = ws + 262144;      // 131072
    float* gp      = ws + 393216;      // 524288 -> 917504
    float* C1p     = ws + 917504;      // 2048
    float* C2p     = ws + 919552;      // 2048
    float* kmu     = ws + 921600;      // 65536
    float* krstd   = ws + 987136;      // 65536
    float* vmu     = ws + 1052672;     // 65536
    float* vrstd   = ws + 1118208;     // 65536
    float* Sp      = ws + 1183744;     // 16384
    float* Mp      = ws + 1200128;     // 16384 -> 1216512
    __fp16* slotsh = (__fp16*)(ws + 1216512);   // 65536 float-slots
    __fp16* updh   = (__fp16*)(ws + 1282048);   // 65536
    __fp16* hidh   = (__fp16*)(ws + 1347584);   // 65536 -> 1413120
    uint2* TWqh  = (uint2*)(ws + 1413120);      // 131072 -> 1544192
    uint2* TWihh = (uint2*)(ws + 1544192);      // 393216 -> 1937408
    uint2* TWhhh = (uint2*)(ws + 1937408);      // 393216 -> 2330624
    uint2* TW1h  = (uint2*)(ws + 2330624);      // 131072 -> 2461696
    uint2* TW2h  = (uint2*)(ws + 2461696);      // 131072 -> 2592768 floats = 10.4 MB

    float* out      = (float*)d_out;
    float* attn_out = out + 131072;
    float* pf       = out + 1179648;
    float* sf       = pf + 33554432;
    float* sf2      = sf + 33554432;
    float* Uwp      = pf;                    // 8.4M floats scratch in pf region
    float* gpB      = pf + 16777216;         // 0.5M floats scratch in pf region
    __fp16* kh      = (__fp16*)sf;           // 67 MB f16 k in sf region
    // pf/sf scratch fully consumed before k_features overwrites those regions

    k_pre<<<1024, 256, 0, stream>>>(slots_mu, k_inp, v_inp, slots, slotsh,
                                    kmu, krstd, vmu, vrstd, kh);
    k_wt<<<2304, 256, 0, stream>>>(Wq, W_ih, W_hh, W1, W2, TWqh, TWihh, TWhhh, TW1h, TW2h);

    for (int it = 0; it < 3; it++){
        int last = (it == 2);
        k_ln_q<<<dim3(8,64), 256, 0, stream>>>(slots, gs, bs, TWqh, bq, gk, bk, qg, C1p, C2p);
        k_attn_av<<<dim3(64,16), 256, 0, stream>>>(kh, v_inp, qg, C1p, C2p,
                                                   kmu, krstd, vmu, vrstd,
                                                   Sp, Mp, Uwp, attn_out, last);
        k_upd<<<256, 256, 0, stream>>>(Uwp, Sp, Mp, gv, bv, updh);
        k_gru_mm<<<dim3(32,16,2), 256, 0, stream>>>(updh, slotsh, TWihh, b_ih, TWhhh, b_hh, gp, gpB);
        k_tail1<<<dim3(8,64), 256, 0, stream>>>(gp, gpB, slots, gff, bff, TW1h, b1, slots2, hidh);
        k_ffn2<<<dim3(8,64), 256, 0, stream>>>(hidh, TW2h, b2, slots2, slots, slotsh, out, last);
    }

    k_features<<<dim3(128,16), 256, 0, stream>>>(prompts, slots, attn_out, pf, sf, sf2);
}

// Round 13
// 723.551 us; speedup vs baseline: 8.8667x; 1.0289x over previous
//
#include <hip/hip_runtime.h>
#include <math.h>

#define NN 4096
#define DD 512
#define NSL 16
#define SCALE_F 0.044194173824159216f
#define LN_EPS_F 1e-5f
#define ATTN_EPS_F 1e-8f

typedef float4 f4;
typedef __fp16 h2 __attribute__((ext_vector_type(2)));
typedef _Float16 h2f __attribute__((ext_vector_type(2)));

__device__ __forceinline__ float dot4f(f4 a, f4 b){
    return a.x*b.x + a.y*b.y + a.z*b.z + a.w*b.w;
}
__device__ __forceinline__ float fdot2u(unsigned a, unsigned b, float c){
    return __builtin_amdgcn_fdot2(__builtin_bit_cast(h2f, a),
                                  __builtin_bit_cast(h2f, b), c, false);
}
__device__ __forceinline__ unsigned pk(float x, float y){
    return __builtin_bit_cast(unsigned, __builtin_amdgcn_cvt_pkrtz(x, y));
}

// ---- prep: slots bcast + row stats + f16 copies of k,v + weight transpose ----
// grid 1024 x 256.
__global__ __launch_bounds__(256) void k_prep(const float* __restrict__ mu,
        const float* __restrict__ kin, const float* __restrict__ vin,
        float* __restrict__ slots, __fp16* __restrict__ slotsh,
        float* __restrict__ kmu, float* __restrict__ krstd,
        float* __restrict__ vmu, float* __restrict__ vrstd,
        __fp16* __restrict__ kh, __fp16* __restrict__ vh,
        const float* __restrict__ Wq, const float* __restrict__ Wih,
        const float* __restrict__ Whh, const float* __restrict__ W1,
        const float* __restrict__ W2,
        uint2* __restrict__ TWq, uint2* __restrict__ TWih, uint2* __restrict__ TWhh,
        uint2* __restrict__ TW1, uint2* __restrict__ TW2){
    int bx = blockIdx.x, t = threadIdx.x;
    int gid = bx*256 + t;
    if (bx < 128){
        int idx = gid;                             // 32768 f4
        f4 v = ((const f4*)mu)[idx & 2047];
        ((f4*)slots)[idx] = v;
        uint2 o; o.x = pk(v.x, v.y); o.y = pk(v.z, v.w);
        ((uint2*)slotsh)[idx] = o;
    }
    int sub = t & 15;
    int rl  = t >> 4;
#pragma unroll
    for (int pass = 0; pass < 8; pass++){
        int task = bx*128 + pass*16 + rl;          // 0..131071
        int half = task >> 16;                     // 0: v, 1: k
        int row  = task & 65535;
        const float* src = half ? kin : vin;
        __fp16* dsth = half ? kh : vh;
        const f4* r4 = (const f4*)(src + (size_t)row*DD);
        uint2* w2 = (uint2*)(dsth + (size_t)row*DD);
        float s = 0.f, ss = 0.f;
#pragma unroll
        for (int k2 = 0; k2 < 8; k2++){
            f4 x = r4[sub + k2*16];
            s  += x.x+x.y+x.z+x.w;
            ss += x.x*x.x+x.y*x.y+x.z*x.z+x.w*x.w;
            uint2 o; o.x = pk(x.x, x.y); o.y = pk(x.z, x.w);
            w2[sub + k2*16] = o;
        }
        for (int o = 1; o < 16; o <<= 1){
            s += __shfl_xor(s, o); ss += __shfl_xor(ss, o);
        }
        if (sub == 0){
            float m = s*(1.f/DD);
            float rs = rsqrtf(ss*(1.f/DD) - m*m + LN_EPS_F);
            if (half){ kmu[row] = m; krstd[row] = rs; }
            else     { vmu[row] = m; vrstd[row] = rs; }
        }
    }
    // weight transpose-pack (f16): 589824 uint2 across 262144 threads
    for (int id = gid; id < 589824; id += 262144){
        const float* W; uint2* TW; int R, local;
        if (id < 65536)      { W = Wq;  TW = TWq;  R = 512;  local = id; }
        else if (id < 262144){ W = Wih; TW = TWih; R = 1536; local = id - 65536; }
        else if (id < 458752){ W = Whh; TW = TWhh; R = 1536; local = id - 262144; }
        else if (id < 524288){ W = W1;  TW = TW1;  R = 512;  local = id - 458752; }
        else                 { W = W2;  TW = TW2;  R = 512;  local = id - 524288; }
        int kk = local / R, c = local - kk*R;
        f4 w = ((const f4*)W)[(size_t)c*128 + kk];
        uint2 o; o.x = pk(w.x, w.y); o.y = pk(w.z, w.w);
        TW[local] = o;
    }
}

// ---- fused LN(slots) + q-projection -> qgh (f16) ----
__global__ __launch_bounds__(256) void k_ln_q(const float* __restrict__ slots,
        const float* __restrict__ gs, const float* __restrict__ bs,
        const uint2* __restrict__ TWq, const float* __restrict__ bq,
        const float* __restrict__ gk, const float* __restrict__ bk,
        __fp16* __restrict__ qgh, float* __restrict__ C1p, float* __restrict__ C2p){
    __shared__ uint2 rowh[4][128];                // per-wave normalized row, f16
    int lane = threadIdx.x & 63, wv = threadIdx.x >> 6;
    int m = blockIdx.y*4 + wv;
    int c = blockIdx.x*64 + lane;
    const f4* r4 = (const f4*)(slots + (size_t)m*DD);
    f4 v0 = r4[lane*2], v1 = r4[lane*2+1];
    float s  = v0.x+v0.y+v0.z+v0.w + v1.x+v1.y+v1.z+v1.w;
    float ss = v0.x*v0.x+v0.y*v0.y+v0.z*v0.z+v0.w*v0.w
             + v1.x*v1.x+v1.y*v1.y+v1.z*v1.z+v1.w*v1.w;
    for (int o = 32; o; o >>= 1){ s += __shfl_down(s,o); ss += __shfl_down(ss,o); }
    s = __shfl(s,0); ss = __shfl(ss,0);
    float mu = s*(1.f/DD);
    float rstd = rsqrtf(ss*(1.f/DD) - mu*mu + LN_EPS_F);
    const f4* g4 = (const f4*)gs; const f4* b4 = (const f4*)bs;
    f4 g0 = g4[lane*2], g1 = g4[lane*2+1], c0 = b4[lane*2], c1 = b4[lane*2+1];
    f4 o0, o1;
    o0.x=(v0.x-mu)*rstd*g0.x+c0.x; o0.y=(v0.y-mu)*rstd*g0.y+c0.y;
    o0.z=(v0.z-mu)*rstd*g0.z+c0.z; o0.w=(v0.w-mu)*rstd*g0.w+c0.w;
    o1.x=(v1.x-mu)*rstd*g1.x+c1.x; o1.y=(v1.y-mu)*rstd*g1.y+c1.y;
    o1.z=(v1.z-mu)*rstd*g1.z+c1.z; o1.w=(v1.w-mu)*rstd*g1.w+c1.w;
    rowh[wv][lane*2]     = uint2{pk(o0.x,o0.y), pk(o0.z,o0.w)};
    rowh[wv][lane*2 + 1] = uint2{pk(o1.x,o1.y), pk(o1.z,o1.w)};
    __syncthreads();
    float acc = 0.f;
    for (int kk = 0; kk < 128; kk++){
        uint2 q2 = rowh[wv][kk];
        uint2 w2 = TWq[(size_t)kk*512 + c];
        acc = fdot2u(w2.x, q2.x, acc);
        acc = fdot2u(w2.y, q2.y, acc);
    }
    float q0 = acc + bq[c];
    float qg0 = q0 * gk[c];
    float qg1 = __shfl_down(qg0, 1);
    if (!(lane & 1))
        ((unsigned*)qgh)[(size_t)m*256 + (c>>1)] = pk(qg0, qg1);
    float r1 = qg0, r2 = q0 * bk[c];
    for (int o = 32; o; o >>= 1){ r1 += __shfl_down(r1,o); r2 += __shfl_down(r2,o); }
    if (lane == 0){
        C1p[blockIdx.x*256 + m] = r1;
        C2p[blockIdx.x*256 + m] = r2;
    }
}

// ---- fused QK^T + inverted softmax + AV partial (all f16 streams) ----
__global__ __launch_bounds__(256, 4) void k_attn_av(const __fp16* __restrict__ kh,
        const __fp16* __restrict__ vh, const __fp16* __restrict__ qgh,
        const float* __restrict__ C1p, const float* __restrict__ C2p,
        const float* __restrict__ kmu, const float* __restrict__ krstd,
        const float* __restrict__ vmu, const float* __restrict__ vrstd,
        float* __restrict__ Sp, float* __restrict__ Mp, __fp16* __restrict__ Uwp,
        float* __restrict__ attn_out, int last){
    __shared__ __align__(16) uint4 qhL[1024];      // 16 KB packed f16 q
    __shared__ __align__(16) float wL[64*20];      // 5 KB
    __shared__ float c1s[NSL], c2s[NSL];
    __shared__ float spL[4][NSL], mpL[4][NSL];
    int chunk = blockIdx.x, b = blockIdx.y;
    int t = threadIdx.x, lane = t & 63, wv = t >> 6;
    int r = lane & 15, qq = lane >> 4;

    const uint2* qgg2 = (const uint2*)(qgh + (size_t)b*NSL*DD);  // 128 uint2/row
    for (int e = t; e < 1024; e += 256){
        int dd = e >> 3, p = e & 7;
        uint2 A = qgg2[(size_t)(2*p)*128 + dd];
        uint2 B = qgg2[(size_t)(2*p+1)*128 + dd];
        qhL[e] = uint4{A.x, B.x, A.y, B.y};
    }
    if (t < NSL){
        float c1 = 0.f, c2 = 0.f;
#pragma unroll
        for (int k = 0; k < 8; k++){
            c1 += C1p[k*256 + b*NSL + t];
            c2 += C2p[k*256 + b*NSL + t];
        }
        c1s[t] = c1; c2s[t] = c2;
    }
    __syncthreads();

    int j = chunk*64 + wv*16 + r;
    const uint4* kr = (const uint4*)(kh + ((size_t)b*NN + j)*DD) + qq*16;
    float a[NSL];
#pragma unroll
    for (int i = 0; i < NSL; i++) a[i] = 0.f;
    uint4 kb = kr[0];
    for (int e = 0; e < 16; e++){
        uint4 nk;
        if (e < 15) nk = kr[e+1];
        int dd0 = qq*32 + e*2;
#pragma unroll
        for (int p = 0; p < 8; p++){
            uint4 u = qhL[dd0*8 + p];
            a[2*p]   = fdot2u(kb.x, u.x, a[2*p]);
            a[2*p+1] = fdot2u(kb.x, u.y, a[2*p+1]);
            a[2*p]   = fdot2u(kb.y, u.z, a[2*p]);
            a[2*p+1] = fdot2u(kb.y, u.w, a[2*p+1]);
            uint4 u2 = qhL[(dd0+1)*8 + p];
            a[2*p]   = fdot2u(kb.z, u2.x, a[2*p]);
            a[2*p+1] = fdot2u(kb.z, u2.y, a[2*p+1]);
            a[2*p]   = fdot2u(kb.w, u2.z, a[2*p]);
            a[2*p+1] = fdot2u(kb.w, u2.w, a[2*p+1]);
        }
        kb = nk;
    }
#pragma unroll
    for (int i = 0; i < NSL; i++){
        a[i] += __shfl_xor(a[i], 16);
        a[i] += __shfl_xor(a[i], 32);
    }
    float mu = kmu[(size_t)b*NN + j];
    float rstd = krstd[(size_t)b*NN + j];
    float mx = -1e30f;
#pragma unroll
    for (int i = 0; i < NSL; i++){
        a[i] = SCALE_F*(rstd*(a[i] - mu*c1s[i]) + c2s[i]);
        mx = fmaxf(mx, a[i]);
    }
    float se = 0.f;
#pragma unroll
    for (int i = 0; i < NSL; i++){ a[i] = __expf(a[i]-mx); se += a[i]; }
    float inv = 1.f/se;
    float rv = vrstd[(size_t)b*NN + j];
    float vm = vmu[(size_t)b*NN + j];
#pragma unroll
    for (int i = 0; i < NSL; i++) a[i] = a[i]*inv + ATTN_EPS_F;
#pragma unroll
    for (int i = 0; i < NSL; i++){
        float r1 = a[i], r2 = a[i]*rv*vm;
        for (int o = 1; o < 16; o <<= 1){ r1 += __shfl_xor(r1,o); r2 += __shfl_xor(r2,o); }
        if (lane == 0){ spL[wv][i] = r1; mpL[wv][i] = r2; }
    }
    if (qq == 0){
        int jl = wv*16 + r;
#pragma unroll
        for (int i = 0; i < NSL; i++) wL[jl*20 + i] = a[i]*rv;
        if (last){
#pragma unroll
            for (int i = 0; i < NSL; i++)
                attn_out[((size_t)b*NSL + i)*NN + j] = a[i];
        }
    }
    __syncthreads();

    if (t < NSL)
        Sp[((size_t)b*NSL + t)*64 + chunk] = spL[0][t]+spL[1][t]+spL[2][t]+spL[3][t];
    else if (t < 2*NSL){
        int i = t - NSL;
        Mp[((size_t)b*NSL + i)*64 + chunk] = mpL[0][i]+mpL[1][i]+mpL[2][i]+mpL[3][i];
    }

    // ---- AV partial over this chunk's 64 j (f16 v) ----
    f4 ax[4], ay[4];
#pragma unroll
    for (int g2 = 0; g2 < 4; g2++){ ax[g2] = f4{0,0,0,0}; ay[g2] = f4{0,0,0,0}; }
    const unsigned* v2h = (const unsigned*)(vh + ((size_t)b*NN + (size_t)chunk*64)*DD);
#pragma unroll 2
    for (int jj = 0; jj < 64; jj++){
        unsigned vu = v2h[(size_t)jj*256 + t];
        h2 hv = __builtin_bit_cast(h2, vu);
        float vx = (float)hv.x, vy = (float)hv.y;
        const f4* wl4 = (const f4*)(wL + jj*20);
#pragma unroll
        for (int g2 = 0; g2 < 4; g2++){
            f4 wq = wl4[g2];
            ax[g2].x += wq.x*vx; ax[g2].y += wq.y*vx; ax[g2].z += wq.z*vx; ax[g2].w += wq.w*vx;
            ay[g2].x += wq.x*vy; ay[g2].y += wq.y*vy; ay[g2].z += wq.z*vy; ay[g2].w += wq.w*vy;
        }
    }
#pragma unroll
    for (int g2 = 0; g2 < 4; g2++){
        const float* px = (const float*)&ax[g2];
        const float* py = (const float*)&ay[g2];
#pragma unroll
        for (int c4 = 0; c4 < 4; c4++){
            int i = g2*4 + c4;
            ((unsigned*)Uwp)[(((size_t)(b*NSL + i))*64 + chunk)*256 + t] = pk(px[c4], py[c4]);
        }
    }
}

// ---- updates = gv*(sum Uwp - M)/S + bv -> updh (f16)  (block = row m) ----
__global__ __launch_bounds__(256) void k_upd(const __fp16* __restrict__ Uwp,
        const float* __restrict__ Sp, const float* __restrict__ Mp,
        const float* __restrict__ gv, const float* __restrict__ bv,
        __fp16* __restrict__ updh){
    __shared__ float sm[2];
    int m = blockIdx.x, t = threadIdx.x;
    if (t < 128){
        float val = (t < 64) ? Sp[(size_t)m*64 + (t&63)] : Mp[(size_t)m*64 + (t&63)];
        for (int o = 1; o < 64; o <<= 1) val += __shfl_xor(val, o);
        if (t == 0)  sm[0] = val;
        if (t == 64) sm[1] = val;
    }
    __syncthreads();
    float Sv = sm[0], Mv = sm[1];
    float rS = 1.f/Sv;
    float accx = 0.f, accy = 0.f;
    const unsigned* base = (const unsigned*)Uwp + (size_t)m*64*256 + t;
#pragma unroll 8
    for (int ch = 0; ch < 64; ch++){
        h2 u = __builtin_bit_cast(h2, base[(size_t)ch*256]);
        accx += (float)u.x; accy += (float)u.y;
    }
    float2 gvv = ((const float2*)gv)[t];
    float2 bvv = ((const float2*)bv)[t];
    float ox = gvv.x*(accx - Mv)*rS + bvv.x;
    float oy = gvv.y*(accy - Mv)*rS + bvv.y;
    ((unsigned*)updh)[(size_t)m*256 + t] = pk(ox, oy);
}

// ---- GRU gate matmuls, f16 + split-K x2: grid (32 cc, 16 mg, 2 ks) ----
__global__ __launch_bounds__(256) void k_gru_mm(const __fp16* __restrict__ xh, const __fp16* __restrict__ hh,
        const uint2* __restrict__ TWih, const float* __restrict__ bih,
        const uint2* __restrict__ TWhh, const float* __restrict__ bhh,
        float* __restrict__ gpA, float* __restrict__ gpB){
    int lane = threadIdx.x & 63, wv = threadIdx.x >> 6;
    int c = blockIdx.x*64 + lane;                 // 0..2047
    int m0 = blockIdx.y*16 + wv*4;
    int ks = blockIdx.z;
    int k0 = ks*64, k1 = k0 + 64;
    float* gp = ks ? gpB : gpA;
    int type = c >> 9;
    const uint2* x2 = (const uint2*)xh;
    const uint2* h2_ = (const uint2*)hh;
    float acc[4] = {0,0,0,0};
    float bias;
    if (type <= 1){
        for (int kk = k0; kk < k1; kk++){
            uint2 wa = TWih[(size_t)kk*1536 + c];
            uint2 wb = TWhh[(size_t)kk*1536 + c];
#pragma unroll
            for (int mm = 0; mm < 4; mm++){
                uint2 xa = x2[(size_t)(m0+mm)*128 + kk];
                uint2 ha = h2_[(size_t)(m0+mm)*128 + kk];
                acc[mm] = fdot2u(wa.x, xa.x, acc[mm]);
                acc[mm] = fdot2u(wa.y, xa.y, acc[mm]);
                acc[mm] = fdot2u(wb.x, ha.x, acc[mm]);
                acc[mm] = fdot2u(wb.y, ha.y, acc[mm]);
            }
        }
        bias = bih[c] + bhh[c];
    } else if (type == 2){
        for (int kk = k0; kk < k1; kk++){
            uint2 wa = TWih[(size_t)kk*1536 + c];
#pragma unroll
            for (int mm = 0; mm < 4; mm++){
                uint2 xa = x2[(size_t)(m0+mm)*128 + kk];
                acc[mm] = fdot2u(wa.x, xa.x, acc[mm]);
                acc[mm] = fdot2u(wa.y, xa.y, acc[mm]);
            }
        }
        bias = bih[c];
    } else {
        int cr = c - 512;
        for (int kk = k0; kk < k1; kk++){
            uint2 wb = TWhh[(size_t)kk*1536 + cr];
#pragma unroll
            for (int mm = 0; mm < 4; mm++){
                uint2 ha = h2_[(size_t)(m0+mm)*128 + kk];
                acc[mm] = fdot2u(wb.x, ha.x, acc[mm]);
                acc[mm] = fdot2u(wb.y, ha.y, acc[mm]);
            }
        }
        bias = bhh[cr];
    }
    float bout = ks ? 0.f : bias;
#pragma unroll
    for (int mm = 0; mm < 4; mm++)
        gp[(size_t)(m0+mm)*2048 + c] = acc[mm] + bout;
}

// ---- tail1: GRU-elem + LN(gff,bff) + FFN1 -> hidh; cc==0 writes slots2 ----
__global__ __launch_bounds__(256) void k_tail1(const float* __restrict__ gpA,
        const float* __restrict__ gpB, const float* __restrict__ slots,
        const float* __restrict__ gff, const float* __restrict__ bff,
        const uint2* __restrict__ TW1, const float* __restrict__ b1,
        float* __restrict__ slots2, __fp16* __restrict__ hidh){
    __shared__ uint2 rowh[4][128];
    int lane = threadIdx.x & 63, wv = threadIdx.x >> 6;
    int m = blockIdx.y*4 + wv;
    int c = blockIdx.x*64 + lane;
    const f4* g0 = (const f4*)(gpA + (size_t)m*2048);
    const f4* g1 = (const f4*)(gpB + (size_t)m*2048);
    const f4* h4 = (const f4*)(slots + (size_t)m*DD);
    f4 s2v[2];
    float s = 0.f, ss = 0.f;
#pragma unroll
    for (int half = 0; half < 2; half++){
        int e = lane*2 + half;
        f4 rp = g0[e],      zp = g0[128+e],  nx = g0[256+e],  nh = g0[384+e];
        f4 rq = g1[e],      zq = g1[128+e],  ny = g1[256+e],  nz = g1[384+e];
        rp.x+=rq.x; rp.y+=rq.y; rp.z+=rq.z; rp.w+=rq.w;
        zp.x+=zq.x; zp.y+=zq.y; zp.z+=zq.z; zp.w+=zq.w;
        nx.x+=ny.x; nx.y+=ny.y; nx.z+=ny.z; nx.w+=ny.w;
        nh.x+=nz.x; nh.y+=nz.y; nh.z+=nz.z; nh.w+=nz.w;
        f4 hv = h4[e];
        f4 o;
        {
            float r = 1.f/(1.f + __expf(-rp.x));
            float z = 1.f/(1.f + __expf(-zp.x));
            float n = tanhf(nx.x + r*nh.x);
            o.x = (1.f - z)*n + z*hv.x;
            r = 1.f/(1.f + __expf(-rp.y)); z = 1.f/(1.f + __expf(-zp.y));
            n = tanhf(nx.y + r*nh.y);
            o.y = (1.f - z)*n + z*hv.y;
            r = 1.f/(1.f + __expf(-rp.z)); z = 1.f/(1.f + __expf(-zp.z));
            n = tanhf(nx.z + r*nh.z);
            o.z = (1.f - z)*n + z*hv.z;
            r = 1.f/(1.f + __expf(-rp.w)); z = 1.f/(1.f + __expf(-zp.w));
            n = tanhf(nx.w + r*nh.w);
            o.w = (1.f - z)*n + z*hv.w;
        }
        s2v[half] = o;
        s  += o.x+o.y+o.z+o.w;
        ss += o.x*o.x+o.y*o.y+o.z*o.z+o.w*o.w;
        if (blockIdx.x == 0)
            ((f4*)(slots2 + (size_t)m*DD))[e] = o;
    }
    for (int o = 32; o; o >>= 1){ s += __shfl_down(s,o); ss += __shfl_down(ss,o); }
    s = __shfl(s,0); ss = __shfl(ss,0);
    float mu = s*(1.f/DD);
    float rstd = rsqrtf(ss*(1.f/DD) - mu*mu + LN_EPS_F);
    const f4* gg4 = (const f4*)gff; const f4* bb4 = (const f4*)bff;
#pragma unroll
    for (int half = 0; half < 2; half++){
        int e = lane*2 + half;
        f4 gg = gg4[e], bb = bb4[e], o = s2v[half], n;
        n.x = (o.x-mu)*rstd*gg.x + bb.x;
        n.y = (o.y-mu)*rstd*gg.y + bb.y;
        n.z = (o.z-mu)*rstd*gg.z + bb.z;
        n.w = (o.w-mu)*rstd*gg.w + bb.w;
        rowh[wv][e] = uint2{pk(n.x,n.y), pk(n.z,n.w)};
    }
    __syncthreads();
    float acc = 0.f;
    for (int kk = 0; kk < 128; kk++){
        uint2 q2 = rowh[wv][kk];
        uint2 w2 = TW1[(size_t)kk*512 + c];
        acc = fdot2u(w2.x, q2.x, acc);
        acc = fdot2u(w2.y, q2.y, acc);
    }
    float hv = fmaxf(acc + b1[c], 0.f);
    hidh[(size_t)m*DD + c] = (__fp16)hv;
}

// ---- FFN2: f16 hid/W2 + slots2 residual -> slots f32 + slotsh f16 (+out) ----
__global__ __launch_bounds__(256) void k_ffn2(const __fp16* __restrict__ hidh, const uint2* __restrict__ TW2,
                                              const float* __restrict__ b2, const float* __restrict__ slots2,
                                              float* __restrict__ slots, __fp16* __restrict__ slotsh,
                                              float* __restrict__ out_slots, int last){
    int lane = threadIdx.x & 63, wv = threadIdx.x >> 6;
    int d = blockIdx.x*64 + lane;
    int m = blockIdx.y*4 + wv;
    const uint2* h2_ = (const uint2*)(hidh + (size_t)m*DD);
    float acc = 0.f;
    for (int kk = 0; kk < 128; kk++){
        uint2 hh = h2_[kk];
        uint2 w2 = TW2[(size_t)kk*512 + d];
        acc = fdot2u(w2.x, hh.x, acc);
        acc = fdot2u(w2.y, hh.y, acc);
    }
    float v0 = slots2[(size_t)m*DD + d] + acc + b2[d];
    slots[(size_t)m*DD + d] = v0;
    slotsh[(size_t)m*DD + d] = (__fp16)v0;
    if (last) out_slots[(size_t)m*DD + d] = v0;
}

// ---- features ----
__global__ __launch_bounds__(256) void k_features(const float* __restrict__ prompts, const float* __restrict__ slots,
        const float* __restrict__ attn, float* __restrict__ pf, float* __restrict__ sf, float* __restrict__ sf2){
    int b = blockIdx.y;
    int pbase = blockIdx.x*32;
    int t = threadIdx.x;
    __shared__ float al[NSL][33];
    for (int idx = t; idx < NSL*32; idx += 256){
        int i = idx >> 5, pp = idx & 31;
        al[i][pp] = attn[((size_t)b*NSL + i)*NN + pbase + pp];
    }
    float2 pr[NSL], sl[NSL];
    const float2* p2 = (const float2*)prompts;
    const float2* s2 = (const float2*)(slots + (size_t)b*NSL*DD);
#pragma unroll
    for (int i = 0; i < NSL; i++){ pr[i] = p2[i*256+t]; sl[i] = s2[i*256+t]; }
    __syncthreads();
    for (int pp = 0; pp < 32; pp++){
        float a0=0.f, a1=0.f, c0=0.f, c1=0.f;
#pragma unroll
        for (int i = 0; i < NSL; i++){
            float a = al[i][pp];
            a0 += a*pr[i].x; a1 += a*pr[i].y;
            c0 += a*sl[i].x; c1 += a*sl[i].y;
        }
        size_t o = ((size_t)b*NN + pbase + pp)*DD + 2*t;
        float2 pv; pv.x=a0; pv.y=a1;
        float2 sv; sv.x=c0; sv.y=c1;
        *(float2*)(pf + o)  = pv;
        *(float2*)(sf + o)  = sv;
        *(float2*)(sf2 + o) = sv;
    }
}

extern "C" void kernel_launch(void* const* d_in, const int* in_sizes, int n_in,
                              void* d_out, int out_size, void* d_ws, size_t ws_size,
                              hipStream_t stream) {
    const float* k_inp   = (const float*)d_in[2];
    const float* v_inp   = (const float*)d_in[3];
    const float* slots_mu= (const float*)d_in[4];
    const float* prompts = (const float*)d_in[5];
    const float* Wq      = (const float*)d_in[6];
    const float* bq      = (const float*)d_in[7];
    const float* W_ih    = (const float*)d_in[8];
    const float* b_ih    = (const float*)d_in[9];
    const float* W_hh    = (const float*)d_in[10];
    const float* b_hh    = (const float*)d_in[11];
    const float* W1      = (const float*)d_in[12];
    const float* b1      = (const float*)d_in[13];
    const float* W2      = (const float*)d_in[14];
    const float* b2      = (const float*)d_in[15];
    const float* gk      = (const float*)d_in[16];
    const float* bk      = (const float*)d_in[17];
    const float* gv      = (const float*)d_in[18];
    const float* bv      = (const float*)d_in[19];
    const float* gs      = (const float*)d_in[20];
    const float* bs      = (const float*)d_in[21];
    const float* gff     = (const float*)d_in[22];
    const float* bff     = (const float*)d_in[23];

    float* ws = (float*)d_ws;
    float* slots   = ws + 0;           // 131072
    float* slots2  = ws + 131072;      // 131072
    float* gp      = ws + 262144;      // 524288 -> 786432
    float* C1p     = ws + 786432;      // 2048
    float* C2p     = ws + 788480;      // 2048
    float* kmu     = ws + 790528;      // 65536
    float* krstd   = ws + 856064;      // 65536
    float* vmu     = ws + 921600;      // 65536
    float* vrstd   = ws + 987136;      // 65536
    float* Sp      = ws + 1052672;     // 16384
    float* Mp      = ws + 1069056;     // 16384 -> 1085440
    __fp16* slotsh = (__fp16*)(ws + 1085440);   // 65536 float-slots
    __fp16* updh   = (__fp16*)(ws + 1150976);   // 65536
    __fp16* hidh   = (__fp16*)(ws + 1216512);   // 65536
    __fp16* qgh    = (__fp16*)(ws + 1282048);   // 65536 -> 1347584
    uint2* TWqh  = (uint2*)(ws + 1347584);      // 131072 -> 1478656
    uint2* TWihh = (uint2*)(ws + 1478656);      // 393216 -> 1871872
    uint2* TWhhh = (uint2*)(ws + 1871872);      // 393216 -> 2265088
    uint2* TW1h  = (uint2*)(ws + 2265088);      // 131072 -> 2396160
    uint2* TW2h  = (uint2*)(ws + 2396160);      // 131072 -> 2527232 floats = 10.1 MB

    float* out      = (float*)d_out;
    float* attn_out = out + 131072;
    float* pf       = out + 1179648;
    float* sf       = pf + 33554432;
    float* sf2      = sf + 33554432;
    __fp16* Uwp     = (__fp16*)pf;           // 8.4M f16 scratch in pf region
    float* gpB      = pf + 16777216;         // 0.5M floats scratch in pf region
    __fp16* kh      = (__fp16*)sf;           // 67 MB f16 k in sf region
    __fp16* vh      = (__fp16*)sf2;          // 67 MB f16 v in sf2 region
    // pf/sf/sf2 scratch fully consumed before k_features overwrites those regions

    k_prep<<<1024, 256, 0, stream>>>(slots_mu, k_inp, v_inp, slots, slotsh,
                                     kmu, krstd, vmu, vrstd, kh, vh,
                                     Wq, W_ih, W_hh, W1, W2,
                                     TWqh, TWihh, TWhhh, TW1h, TW2h);

    for (int it = 0; it < 3; it++){
        int last = (it == 2);
        k_ln_q<<<dim3(8,64), 256, 0, stream>>>(slots, gs, bs, TWqh, bq, gk, bk, qgh, C1p, C2p);
        k_attn_av<<<dim3(64,16), 256, 0, stream>>>(kh, vh, qgh, C1p, C2p,
                                                   kmu, krstd, vmu, vrstd,
                                                   Sp, Mp, Uwp, attn_out, last);
        k_upd<<<256, 256, 0, stream>>>(Uwp, Sp, Mp, gv, bv, updh);
        k_gru_mm<<<dim3(32,16,2), 256, 0, stream>>>(updh, slotsh, TWihh, b_ih, TWhhh, b_hh, gp, gpB);
        k_tail1<<<dim3(8,64), 256, 0, stream>>>(gp, gpB, slots, gff, bff, TW1h, b1, slots2, hidh);
        k_ffn2<<<dim3(8,64), 256, 0, stream>>>(hidh, TW2h, b2, slots2, slots, slotsh, out, last);
    }

    k_features<<<dim3(128,16), 256, 0, stream>>>(prompts, slots, attn_out, pf, sf, sf2);
}

// Round 14
// 558.299 us; speedup vs baseline: 11.4912x; 1.2960x over previous
//
#include <hip/hip_runtime.h>
#include <math.h>

#define NN 4096
#define DD 512
#define NSL 16
#define SCALE_F 0.044194173824159216f
#define LN_EPS_F 1e-5f
#define ATTN_EPS_F 1e-8f

typedef float4 f4;
typedef __fp16 h2 __attribute__((ext_vector_type(2)));
typedef _Float16 h2f __attribute__((ext_vector_type(2)));
typedef _Float16 h8 __attribute__((ext_vector_type(8)));
typedef float f32x4 __attribute__((ext_vector_type(4)));

__device__ __forceinline__ float dot4f(f4 a, f4 b){
    return a.x*b.x + a.y*b.y + a.z*b.z + a.w*b.w;
}
__device__ __forceinline__ float fdot2u(unsigned a, unsigned b, float c){
    return __builtin_amdgcn_fdot2(__builtin_bit_cast(h2f, a),
                                  __builtin_bit_cast(h2f, b), c, false);
}
__device__ __forceinline__ unsigned pk(float x, float y){
    return __builtin_bit_cast(unsigned, __builtin_amdgcn_cvt_pkrtz(x, y));
}

// ---- prep: slots bcast + row stats + f16 copies of k,v + weight transpose ----
__global__ __launch_bounds__(256) void k_prep(const float* __restrict__ mu,
        const float* __restrict__ kin, const float* __restrict__ vin,
        float* __restrict__ slots, __fp16* __restrict__ slotsh,
        float* __restrict__ kmu, float* __restrict__ krstd,
        float* __restrict__ vmu, float* __restrict__ vrstd,
        __fp16* __restrict__ kh, __fp16* __restrict__ vh,
        const float* __restrict__ Wq, const float* __restrict__ Wih,
        const float* __restrict__ Whh, const float* __restrict__ W1,
        const float* __restrict__ W2,
        uint2* __restrict__ TWq, uint2* __restrict__ TWih, uint2* __restrict__ TWhh,
        uint2* __restrict__ TW1, uint2* __restrict__ TW2){
    int bx = blockIdx.x, t = threadIdx.x;
    int gid = bx*256 + t;
    if (bx < 128){
        int idx = gid;                             // 32768 f4
        f4 v = ((const f4*)mu)[idx & 2047];
        ((f4*)slots)[idx] = v;
        uint2 o; o.x = pk(v.x, v.y); o.y = pk(v.z, v.w);
        ((uint2*)slotsh)[idx] = o;
    }
    int sub = t & 15;
    int rl  = t >> 4;
#pragma unroll
    for (int pass = 0; pass < 8; pass++){
        int task = bx*128 + pass*16 + rl;          // 0..131071
        int half = task >> 16;                     // 0: v, 1: k
        int row  = task & 65535;
        const float* src = half ? kin : vin;
        __fp16* dsth = half ? kh : vh;
        const f4* r4 = (const f4*)(src + (size_t)row*DD);
        uint2* w2 = (uint2*)(dsth + (size_t)row*DD);
        float s = 0.f, ss = 0.f;
#pragma unroll
        for (int k2 = 0; k2 < 8; k2++){
            f4 x = r4[sub + k2*16];
            s  += x.x+x.y+x.z+x.w;
            ss += x.x*x.x+x.y*x.y+x.z*x.z+x.w*x.w;
            uint2 o; o.x = pk(x.x, x.y); o.y = pk(x.z, x.w);
            w2[sub + k2*16] = o;
        }
        for (int o = 1; o < 16; o <<= 1){
            s += __shfl_xor(s, o); ss += __shfl_xor(ss, o);
        }
        if (sub == 0){
            float m = s*(1.f/DD);
            float rs = rsqrtf(ss*(1.f/DD) - m*m + LN_EPS_F);
            if (half){ kmu[row] = m; krstd[row] = rs; }
            else     { vmu[row] = m; vrstd[row] = rs; }
        }
    }
    // weight transpose-pack (f16)
    for (int id = gid; id < 589824; id += 262144){
        const float* W; uint2* TW; int R, local;
        if (id < 65536)      { W = Wq;  TW = TWq;  R = 512;  local = id; }
        else if (id < 262144){ W = Wih; TW = TWih; R = 1536; local = id - 65536; }
        else if (id < 458752){ W = Whh; TW = TWhh; R = 1536; local = id - 262144; }
        else if (id < 524288){ W = W1;  TW = TW1;  R = 512;  local = id - 458752; }
        else                 { W = W2;  TW = TW2;  R = 512;  local = id - 524288; }
        int kk = local / R, c = local - kk*R;
        f4 w = ((const f4*)W)[(size_t)c*128 + kk];
        uint2 o; o.x = pk(w.x, w.y); o.y = pk(w.z, w.w);
        TW[local] = o;
    }
}

// ---- fused LN(slots) + q-projection -> qgh (f16) ----
__global__ __launch_bounds__(256) void k_ln_q(const float* __restrict__ slots,
        const float* __restrict__ gs, const float* __restrict__ bs,
        const uint2* __restrict__ TWq, const float* __restrict__ bq,
        const float* __restrict__ gk, const float* __restrict__ bk,
        __fp16* __restrict__ qgh, float* __restrict__ C1p, float* __restrict__ C2p){
    __shared__ uint2 rowh[4][128];
    int lane = threadIdx.x & 63, wv = threadIdx.x >> 6;
    int m = blockIdx.y*4 + wv;
    int c = blockIdx.x*64 + lane;
    const f4* r4 = (const f4*)(slots + (size_t)m*DD);
    f4 v0 = r4[lane*2], v1 = r4[lane*2+1];
    float s  = v0.x+v0.y+v0.z+v0.w + v1.x+v1.y+v1.z+v1.w;
    float ss = v0.x*v0.x+v0.y*v0.y+v0.z*v0.z+v0.w*v0.w
             + v1.x*v1.x+v1.y*v1.y+v1.z*v1.z+v1.w*v1.w;
    for (int o = 32; o; o >>= 1){ s += __shfl_down(s,o); ss += __shfl_down(ss,o); }
    s = __shfl(s,0); ss = __shfl(ss,0);
    float mu = s*(1.f/DD);
    float rstd = rsqrtf(ss*(1.f/DD) - mu*mu + LN_EPS_F);
    const f4* g4 = (const f4*)gs; const f4* b4 = (const f4*)bs;
    f4 g0 = g4[lane*2], g1 = g4[lane*2+1], c0 = b4[lane*2], c1 = b4[lane*2+1];
    f4 o0, o1;
    o0.x=(v0.x-mu)*rstd*g0.x+c0.x; o0.y=(v0.y-mu)*rstd*g0.y+c0.y;
    o0.z=(v0.z-mu)*rstd*g0.z+c0.z; o0.w=(v0.w-mu)*rstd*g0.w+c0.w;
    o1.x=(v1.x-mu)*rstd*g1.x+c1.x; o1.y=(v1.y-mu)*rstd*g1.y+c1.y;
    o1.z=(v1.z-mu)*rstd*g1.z+c1.z; o1.w=(v1.w-mu)*rstd*g1.w+c1.w;
    rowh[wv][lane*2]     = uint2{pk(o0.x,o0.y), pk(o0.z,o0.w)};
    rowh[wv][lane*2 + 1] = uint2{pk(o1.x,o1.y), pk(o1.z,o1.w)};
    __syncthreads();
    float acc = 0.f;
    for (int kk = 0; kk < 128; kk++){
        uint2 q2 = rowh[wv][kk];
        uint2 w2 = TWq[(size_t)kk*512 + c];
        acc = fdot2u(w2.x, q2.x, acc);
        acc = fdot2u(w2.y, q2.y, acc);
    }
    float q0 = acc + bq[c];
    float qg0 = q0 * gk[c];
    float qg1 = __shfl_down(qg0, 1);
    if (!(lane & 1))
        ((unsigned*)qgh)[(size_t)m*256 + (c>>1)] = pk(qg0, qg1);
    float r1 = qg0, r2 = q0 * bk[c];
    for (int o = 32; o; o >>= 1){ r1 += __shfl_down(r1,o); r2 += __shfl_down(r2,o); }
    if (lane == 0){
        C1p[blockIdx.x*256 + m] = r1;
        C2p[blockIdx.x*256 + m] = r2;
    }
}

// ---- fused QK^T (MFMA) + inverted softmax + AV partial (paired fdot2) ----
// grid (64 chunks of 64 j, 16 b). Wave = 16 j-rows via one 16x16x32 MFMA chain.
__global__ __launch_bounds__(256, 4) void k_attn_av(const __fp16* __restrict__ kh,
        const __fp16* __restrict__ vh, const __fp16* __restrict__ qgh,
        const float* __restrict__ C1p, const float* __restrict__ C2p,
        const float* __restrict__ kmu, const float* __restrict__ krstd,
        const float* __restrict__ vmu, const float* __restrict__ vrstd,
        float* __restrict__ Sp, float* __restrict__ Mp, __fp16* __restrict__ Uwp,
        float* __restrict__ attn_out, int last){
    __shared__ __align__(16) unsigned qLr[16*260];   // q rows [slot][260 dw] 16.6 KB
    __shared__ __align__(16) unsigned wLp[32*20];    // w j-pairs [pair][16+pad]
    __shared__ float c1s[NSL], c2s[NSL];
    __shared__ float kmuL[64], krsL[64], vmuL[64], vrsL[64];
    __shared__ float spL[4][NSL], mpL[4][NSL];
    int chunk = blockIdx.x, b = blockIdx.y;
    int t = threadIdx.x, lane = t & 63, wv = t >> 6;

    const unsigned* qsrc = (const unsigned*)(qgh + (size_t)b*NSL*DD);
    for (int e = t; e < 4096; e += 256)
        qLr[(e >> 8)*260 + (e & 255)] = qsrc[e];
    if (t < NSL){
        float c1 = 0.f, c2 = 0.f;
#pragma unroll
        for (int k = 0; k < 8; k++){
            c1 += C1p[k*256 + b*NSL + t];
            c2 += C2p[k*256 + b*NSL + t];
        }
        c1s[t] = c1; c2s[t] = c2;
    }
    {
        int grp = t >> 6, j0 = t & 63;
        size_t gidx = (size_t)b*NN + chunk*64 + j0;
        if (grp == 0) kmuL[j0] = kmu[gidx];
        else if (grp == 1) krsL[j0] = krstd[gidx];
        else if (grp == 2) vmuL[j0] = vmu[gidx];
        else vrsL[j0] = vrstd[gidx];
    }
    __syncthreads();

    // ---- QK: MFMA 16x16x32, A = k rows, B = q^T ----
    int i = lane & 15, g = lane >> 4;
    int jbase = chunk*64 + wv*16;
    const uint4* ka = (const uint4*)(kh + ((size_t)b*NN + jbase + i)*DD);
    const uint4* qb4 = (const uint4*)qLr;
    f32x4 acc = {0.f, 0.f, 0.f, 0.f};
#pragma unroll
    for (int ks = 0; ks < 16; ks++){
        uint4 af = ka[ks*4 + g];
        uint4 bf = qb4[i*65 + ks*4 + g];
        acc = __builtin_amdgcn_mfma_f32_16x16x32_f16(
                  __builtin_bit_cast(h8, af), __builtin_bit_cast(h8, bf), acc, 0, 0, 0);
    }
    // lane holds dots[j = jbase + g*4 + r][slot i] in acc[r]
    float c1i = c1s[i], c2i = c2s[i];
    float a4[4], w4v[4];
    float S_part = 0.f, M_part = 0.f;
#pragma unroll
    for (int r = 0; r < 4; r++){
        int jl = g*4 + r;
        float mu = kmuL[wv*16 + jl], rstd = krsL[wv*16 + jl];
        float dv = SCALE_F*(rstd*(acc[r] - mu*c1i) + c2i);
        float mx = dv;
        mx = fmaxf(mx, __shfl_xor(mx, 1));
        mx = fmaxf(mx, __shfl_xor(mx, 2));
        mx = fmaxf(mx, __shfl_xor(mx, 4));
        mx = fmaxf(mx, __shfl_xor(mx, 8));
        float e = __expf(dv - mx);
        float se = e;
        se += __shfl_xor(se, 1);
        se += __shfl_xor(se, 2);
        se += __shfl_xor(se, 4);
        se += __shfl_xor(se, 8);
        float a = e/se + ATTN_EPS_F;
        a4[r] = a;
        float rv = vrsL[wv*16 + jl], vm = vmuL[wv*16 + jl];
        w4v[r] = a*rv;
        S_part += a;
        M_part += a*rv*vm;
    }
    wLp[(wv*8 + g*2)*20 + i]     = pk(w4v[0], w4v[1]);
    wLp[(wv*8 + g*2 + 1)*20 + i] = pk(w4v[2], w4v[3]);
    S_part += __shfl_xor(S_part, 16);
    S_part += __shfl_xor(S_part, 32);
    M_part += __shfl_xor(M_part, 16);
    M_part += __shfl_xor(M_part, 32);
    if (lane < 16){ spL[wv][lane] = S_part; mpL[wv][lane] = M_part; }
    if (last){
#pragma unroll
        for (int r = 0; r < 4; r++)
            attn_out[((size_t)b*NSL + i)*NN + jbase + g*4 + r] = a4[r];
    }
    __syncthreads();

    if (t < NSL)
        Sp[((size_t)b*NSL + t)*64 + chunk] = spL[0][t]+spL[1][t]+spL[2][t]+spL[3][t];
    else if (t < 2*NSL){
        int ii = t - NSL;
        Mp[((size_t)b*NSL + ii)*64 + chunk] = mpL[0][ii]+mpL[1][ii]+mpL[2][ii]+mpL[3][ii];
    }

    // ---- AV partial: paired-j fdot2 over the chunk's 64 j (32 pairs) ----
    f4 ax[4], ay[4];
#pragma unroll
    for (int g2 = 0; g2 < 4; g2++){ ax[g2] = f4{0,0,0,0}; ay[g2] = f4{0,0,0,0}; }
    const unsigned* v2h = (const unsigned*)(vh + ((size_t)b*NN + (size_t)chunk*64)*DD);
#pragma unroll 2
    for (int p = 0; p < 32; p++){
        unsigned vu0 = v2h[(size_t)(2*p)*256 + t];
        unsigned vu1 = v2h[(size_t)(2*p+1)*256 + t];
        unsigned pd0 = __builtin_amdgcn_perm(vu1, vu0, 0x05040100u);
        unsigned pd1 = __builtin_amdgcn_perm(vu1, vu0, 0x07060302u);
        const uint4* wp4 = (const uint4*)(wLp + p*20);
#pragma unroll
        for (int g2 = 0; g2 < 4; g2++){
            uint4 w = wp4[g2];
            ax[g2].x = fdot2u(w.x, pd0, ax[g2].x);
            ax[g2].y = fdot2u(w.y, pd0, ax[g2].y);
            ax[g2].z = fdot2u(w.z, pd0, ax[g2].z);
            ax[g2].w = fdot2u(w.w, pd0, ax[g2].w);
            ay[g2].x = fdot2u(w.x, pd1, ay[g2].x);
            ay[g2].y = fdot2u(w.y, pd1, ay[g2].y);
            ay[g2].z = fdot2u(w.z, pd1, ay[g2].z);
            ay[g2].w = fdot2u(w.w, pd1, ay[g2].w);
        }
    }
#pragma unroll
    for (int g2 = 0; g2 < 4; g2++){
        const float* px = (const float*)&ax[g2];
        const float* py = (const float*)&ay[g2];
#pragma unroll
        for (int c4 = 0; c4 < 4; c4++){
            int ii = g2*4 + c4;
            ((unsigned*)Uwp)[(((size_t)(b*NSL + ii))*64 + chunk)*256 + t] = pk(px[c4], py[c4]);
        }
    }
}

// ---- updates = gv*(sum Uwp - M)/S + bv -> updh (f16)  (block = row m) ----
__global__ __launch_bounds__(256) void k_upd(const __fp16* __restrict__ Uwp,
        const float* __restrict__ Sp, const float* __restrict__ Mp,
        const float* __restrict__ gv, const float* __restrict__ bv,
        __fp16* __restrict__ updh){
    __shared__ float sm[2];
    int m = blockIdx.x, t = threadIdx.x;
    if (t < 128){
        float val = (t < 64) ? Sp[(size_t)m*64 + (t&63)] : Mp[(size_t)m*64 + (t&63)];
        for (int o = 1; o < 64; o <<= 1) val += __shfl_xor(val, o);
        if (t == 0)  sm[0] = val;
        if (t == 64) sm[1] = val;
    }
    __syncthreads();
    float Sv = sm[0], Mv = sm[1];
    float rS = 1.f/Sv;
    float accx = 0.f, accy = 0.f;
    const unsigned* base = (const unsigned*)Uwp + (size_t)m*64*256 + t;
#pragma unroll 8
    for (int ch = 0; ch < 64; ch++){
        h2 u = __builtin_bit_cast(h2, base[(size_t)ch*256]);
        accx += (float)u.x; accy += (float)u.y;
    }
    float2 gvv = ((const float2*)gv)[t];
    float2 bvv = ((const float2*)bv)[t];
    float ox = gvv.x*(accx - Mv)*rS + bvv.x;
    float oy = gvv.y*(accy - Mv)*rS + bvv.y;
    ((unsigned*)updh)[(size_t)m*256 + t] = pk(ox, oy);
}

// ---- GRU gate matmuls, f16 + split-K x2: grid (32 cc, 16 mg, 2 ks) ----
__global__ __launch_bounds__(256) void k_gru_mm(const __fp16* __restrict__ xh, const __fp16* __restrict__ hh,
        const uint2* __restrict__ TWih, const float* __restrict__ bih,
        const uint2* __restrict__ TWhh, const float* __restrict__ bhh,
        float* __restrict__ gpA, float* __restrict__ gpB){
    int lane = threadIdx.x & 63, wv = threadIdx.x >> 6;
    int c = blockIdx.x*64 + lane;                 // 0..2047
    int m0 = blockIdx.y*16 + wv*4;
    int ks = blockIdx.z;
    int k0 = ks*64, k1 = k0 + 64;
    float* gp = ks ? gpB : gpA;
    int type = c >> 9;
    const uint2* x2 = (const uint2*)xh;
    const uint2* h2_ = (const uint2*)hh;
    float acc[4] = {0,0,0,0};
    float bias;
    if (type <= 1){
#pragma unroll 2
        for (int kk = k0; kk < k1; kk++){
            uint2 wa = TWih[(size_t)kk*1536 + c];
            uint2 wb = TWhh[(size_t)kk*1536 + c];
#pragma unroll
            for (int mm = 0; mm < 4; mm++){
                uint2 xa = x2[(size_t)(m0+mm)*128 + kk];
                uint2 ha = h2_[(size_t)(m0+mm)*128 + kk];
                acc[mm] = fdot2u(wa.x, xa.x, acc[mm]);
                acc[mm] = fdot2u(wa.y, xa.y, acc[mm]);
                acc[mm] = fdot2u(wb.x, ha.x, acc[mm]);
                acc[mm] = fdot2u(wb.y, ha.y, acc[mm]);
            }
        }
        bias = bih[c] + bhh[c];
    } else if (type == 2){
#pragma unroll 2
        for (int kk = k0; kk < k1; kk++){
            uint2 wa = TWih[(size_t)kk*1536 + c];
#pragma unroll
            for (int mm = 0; mm < 4; mm++){
                uint2 xa = x2[(size_t)(m0+mm)*128 + kk];
                acc[mm] = fdot2u(wa.x, xa.x, acc[mm]);
                acc[mm] = fdot2u(wa.y, xa.y, acc[mm]);
            }
        }
        bias = bih[c];
    } else {
        int cr = c - 512;
#pragma unroll 2
        for (int kk = k0; kk < k1; kk++){
            uint2 wb = TWhh[(size_t)kk*1536 + cr];
#pragma unroll
            for (int mm = 0; mm < 4; mm++){
                uint2 ha = h2_[(size_t)(m0+mm)*128 + kk];
                acc[mm] = fdot2u(wb.x, ha.x, acc[mm]);
                acc[mm] = fdot2u(wb.y, ha.y, acc[mm]);
            }
        }
        bias = bhh[cr];
    }
    float bout = ks ? 0.f : bias;
#pragma unroll
    for (int mm = 0; mm < 4; mm++)
        gp[(size_t)(m0+mm)*2048 + c] = acc[mm] + bout;
}

// ---- tail1: GRU-elem + LN(gff,bff) + FFN1 -> hidh; cc==0 writes slots2 ----
__global__ __launch_bounds__(256) void k_tail1(const float* __restrict__ gpA,
        const float* __restrict__ gpB, const float* __restrict__ slots,
        const float* __restrict__ gff, const float* __restrict__ bff,
        const uint2* __restrict__ TW1, const float* __restrict__ b1,
        float* __restrict__ slots2, __fp16* __restrict__ hidh){
    __shared__ uint2 rowh[4][128];
    int lane = threadIdx.x & 63, wv = threadIdx.x >> 6;
    int m = blockIdx.y*4 + wv;
    int c = blockIdx.x*64 + lane;
    const f4* g0 = (const f4*)(gpA + (size_t)m*2048);
    const f4* g1 = (const f4*)(gpB + (size_t)m*2048);
    const f4* h4 = (const f4*)(slots + (size_t)m*DD);
    f4 s2v[2];
    float s = 0.f, ss = 0.f;
#pragma unroll
    for (int half = 0; half < 2; half++){
        int e = lane*2 + half;
        f4 rp = g0[e],      zp = g0[128+e],  nx = g0[256+e],  nh = g0[384+e];
        f4 rq = g1[e],      zq = g1[128+e],  ny = g1[256+e],  nz = g1[384+e];
        rp.x+=rq.x; rp.y+=rq.y; rp.z+=rq.z; rp.w+=rq.w;
        zp.x+=zq.x; zp.y+=zq.y; zp.z+=zq.z; zp.w+=zq.w;
        nx.x+=ny.x; nx.y+=ny.y; nx.z+=ny.z; nx.w+=ny.w;
        nh.x+=nz.x; nh.y+=nz.y; nh.z+=nz.z; nh.w+=nz.w;
        f4 hv = h4[e];
        f4 o;
        {
            float r = 1.f/(1.f + __expf(-rp.x));
            float z = 1.f/(1.f + __expf(-zp.x));
            float n = tanhf(nx.x + r*nh.x);
            o.x = (1.f - z)*n + z*hv.x;
            r = 1.f/(1.f + __expf(-rp.y)); z = 1.f/(1.f + __expf(-zp.y));
            n = tanhf(nx.y + r*nh.y);
            o.y = (1.f - z)*n + z*hv.y;
            r = 1.f/(1.f + __expf(-rp.z)); z = 1.f/(1.f + __expf(-zp.z));
            n = tanhf(nx.z + r*nh.z);
            o.z = (1.f - z)*n + z*hv.z;
            r = 1.f/(1.f + __expf(-rp.w)); z = 1.f/(1.f + __expf(-zp.w));
            n = tanhf(nx.w + r*nh.w);
            o.w = (1.f - z)*n + z*hv.w;
        }
        s2v[half] = o;
        s  += o.x+o.y+o.z+o.w;
        ss += o.x*o.x+o.y*o.y+o.z*o.z+o.w*o.w;
        if (blockIdx.x == 0)
            ((f4*)(slots2 + (size_t)m*DD))[e] = o;
    }
    for (int o = 32; o; o >>= 1){ s += __shfl_down(s,o); ss += __shfl_down(ss,o); }
    s = __shfl(s,0); ss = __shfl(ss,0);
    float mu = s*(1.f/DD);
    float rstd = rsqrtf(ss*(1.f/DD) - mu*mu + LN_EPS_F);
    const f4* gg4 = (const f4*)gff; const f4* bb4 = (const f4*)bff;
#pragma unroll
    for (int half = 0; half < 2; half++){
        int e = lane*2 + half;
        f4 gg = gg4[e], bb = bb4[e], o = s2v[half], n;
        n.x = (o.x-mu)*rstd*gg.x + bb.x;
        n.y = (o.y-mu)*rstd*gg.y + bb.y;
        n.z = (o.z-mu)*rstd*gg.z + bb.z;
        n.w = (o.w-mu)*rstd*gg.w + bb.w;
        rowh[wv][e] = uint2{pk(n.x,n.y), pk(n.z,n.w)};
    }
    __syncthreads();
    float acc = 0.f;
    for (int kk = 0; kk < 128; kk++){
        uint2 q2 = rowh[wv][kk];
        uint2 w2 = TW1[(size_t)kk*512 + c];
        acc = fdot2u(w2.x, q2.x, acc);
        acc = fdot2u(w2.y, q2.y, acc);
    }
    float hv = fmaxf(acc + b1[c], 0.f);
    hidh[(size_t)m*DD + c] = (__fp16)hv;
}

// ---- FFN2: f16 hid/W2 + slots2 residual -> slots f32 + slotsh f16 (+out) ----
__global__ __launch_bounds__(256) void k_ffn2(const __fp16* __restrict__ hidh, const uint2* __restrict__ TW2,
                                              const float* __restrict__ b2, const float* __restrict__ slots2,
                                              float* __restrict__ slots, __fp16* __restrict__ slotsh,
                                              float* __restrict__ out_slots, int last){
    int lane = threadIdx.x & 63, wv = threadIdx.x >> 6;
    int d = blockIdx.x*64 + lane;
    int m = blockIdx.y*4 + wv;
    const uint2* h2_ = (const uint2*)(hidh + (size_t)m*DD);
    float acc = 0.f;
    for (int kk = 0; kk < 128; kk++){
        uint2 hh = h2_[kk];
        uint2 w2 = TW2[(size_t)kk*512 + d];
        acc = fdot2u(w2.x, hh.x, acc);
        acc = fdot2u(w2.y, hh.y, acc);
    }
    float v0 = slots2[(size_t)m*DD + d] + acc + b2[d];
    slots[(size_t)m*DD + d] = v0;
    slotsh[(size_t)m*DD + d] = (__fp16)v0;
    if (last) out_slots[(size_t)m*DD + d] = v0;
}

// ---- features ----
__global__ __launch_bounds__(256) void k_features(const float* __restrict__ prompts, const float* __restrict__ slots,
        const float* __restrict__ attn, float* __restrict__ pf, float* __restrict__ sf, float* __restrict__ sf2){
    int b = blockIdx.y;
    int pbase = blockIdx.x*32;
    int t = threadIdx.x;
    __shared__ float al[NSL][33];
    for (int idx = t; idx < NSL*32; idx += 256){
        int i = idx >> 5, pp = idx & 31;
        al[i][pp] = attn[((size_t)b*NSL + i)*NN + pbase + pp];
    }
    float2 pr[NSL], sl[NSL];
    const float2* p2 = (const float2*)prompts;
    const float2* s2 = (const float2*)(slots + (size_t)b*NSL*DD);
#pragma unroll
    for (int i = 0; i < NSL; i++){ pr[i] = p2[i*256+t]; sl[i] = s2[i*256+t]; }
    __syncthreads();
    for (int pp = 0; pp < 32; pp++){
        float a0=0.f, a1=0.f, c0=0.f, c1=0.f;
#pragma unroll
        for (int i = 0; i < NSL; i++){
            float a = al[i][pp];
            a0 += a*pr[i].x; a1 += a*pr[i].y;
            c0 += a*sl[i].x; c1 += a*sl[i].y;
        }
        size_t o = ((size_t)b*NN + pbase + pp)*DD + 2*t;
        float2 pv; pv.x=a0; pv.y=a1;
        float2 sv; sv.x=c0; sv.y=c1;
        *(float2*)(pf + o)  = pv;
        *(float2*)(sf + o)  = sv;
        *(float2*)(sf2 + o) = sv;
    }
}

extern "C" void kernel_launch(void* const* d_in, const int* in_sizes, int n_in,
                              void* d_out, int out_size, void* d_ws, size_t ws_size,
                              hipStream_t stream) {
    const float* k_inp   = (const float*)d_in[2];
    const float* v_inp   = (const float*)d_in[3];
    const float* slots_mu= (const float*)d_in[4];
    const float* prompts = (const float*)d_in[5];
    const float* Wq      = (const float*)d_in[6];
    const float* bq      = (const float*)d_in[7];
    const float* W_ih    = (const float*)d_in[8];
    const float* b_ih    = (const float*)d_in[9];
    const float* W_hh    = (const float*)d_in[10];
    const float* b_hh    = (const float*)d_in[11];
    const float* W1      = (const float*)d_in[12];
    const float* b1      = (const float*)d_in[13];
    const float* W2      = (const float*)d_in[14];
    const float* b2      = (const float*)d_in[15];
    const float* gk      = (const float*)d_in[16];
    const float* bk      = (const float*)d_in[17];
    const float* gv      = (const float*)d_in[18];
    const float* bv      = (const float*)d_in[19];
    const float* gs      = (const float*)d_in[20];
    const float* bs      = (const float*)d_in[21];
    const float* gff     = (const float*)d_in[22];
    const float* bff     = (const float*)d_in[23];

    float* ws = (float*)d_ws;
    float* slots   = ws + 0;           // 131072
    float* slots2  = ws + 131072;      // 131072
    float* gp      = ws + 262144;      // 524288 -> 786432
    float* C1p     = ws + 786432;      // 2048
    float* C2p     = ws + 788480;      // 2048
    float* kmu     = ws + 790528;      // 65536
    float* krstd   = ws + 856064;      // 65536
    float* vmu     = ws + 921600;      // 65536
    float* vrstd   = ws + 987136;      // 65536
    float* Sp      = ws + 1052672;     // 16384
    float* Mp      = ws + 1069056;     // 16384 -> 1085440
    __fp16* slotsh = (__fp16*)(ws + 1085440);   // 65536 float-slots
    __fp16* updh   = (__fp16*)(ws + 1150976);   // 65536
    __fp16* hidh   = (__fp16*)(ws + 1216512);   // 65536
    __fp16* qgh    = (__fp16*)(ws + 1282048);   // 65536 -> 1347584
    uint2* TWqh  = (uint2*)(ws + 1347584);      // 131072 -> 1478656
    uint2* TWihh = (uint2*)(ws + 1478656);      // 393216 -> 1871872
    uint2* TWhhh = (uint2*)(ws + 1871872);      // 393216 -> 2265088
    uint2* TW1h  = (uint2*)(ws + 2265088);      // 131072 -> 2396160
    uint2* TW2h  = (uint2*)(ws + 2396160);      // 131072 -> 2527232 floats = 10.1 MB

    float* out      = (float*)d_out;
    float* attn_out = out + 131072;
    float* pf       = out + 1179648;
    float* sf       = pf + 33554432;
    float* sf2      = sf + 33554432;
    __fp16* Uwp     = (__fp16*)pf;           // 8.4M f16 scratch in pf region
    float* gpB      = pf + 16777216;         // 0.5M floats scratch in pf region
    __fp16* kh      = (__fp16*)sf;           // 67 MB f16 k in sf region
    __fp16* vh      = (__fp16*)sf2;          // 67 MB f16 v in sf2 region
    // pf/sf/sf2 scratch fully consumed before k_features overwrites those regions

    k_prep<<<1024, 256, 0, stream>>>(slots_mu, k_inp, v_inp, slots, slotsh,
                                     kmu, krstd, vmu, vrstd, kh, vh,
                                     Wq, W_ih, W_hh, W1, W2,
                                     TWqh, TWihh, TWhhh, TW1h, TW2h);

    for (int it = 0; it < 3; it++){
        int last = (it == 2);
        k_ln_q<<<dim3(8,64), 256, 0, stream>>>(slots, gs, bs, TWqh, bq, gk, bk, qgh, C1p, C2p);
        k_attn_av<<<dim3(64,16), 256, 0, stream>>>(kh, vh, qgh, C1p, C2p,
                                                   kmu, krstd, vmu, vrstd,
                                                   Sp, Mp, Uwp, attn_out, last);
        k_upd<<<256, 256, 0, stream>>>(Uwp, Sp, Mp, gv, bv, updh);
        k_gru_mm<<<dim3(32,16,2), 256, 0, stream>>>(updh, slotsh, TWihh, b_ih, TWhhh, b_hh, gp, gpB);
        k_tail1<<<dim3(8,64), 256, 0, stream>>>(gp, gpB, slots, gff, bff, TW1h, b1, slots2, hidh);
        k_ffn2<<<dim3(8,64), 256, 0, stream>>>(hidh, TW2h, b2, slots2, slots, slotsh, out, last);
    }

    k_features<<<dim3(128,16), 256, 0, stream>>>(prompts, slots, attn_out, pf, sf, sf2);
}